// Round 14
// baseline (803.736 us; speedup 1.0000x reference)
//
#include <hip/hip_runtime.h>

// ---------------------------------------------------------------------------
// Round 13: R11 base (BM=64, proven) + staging-chain cuts and fusions.
//  - gSe/gOe precomputed per edge inside node_msg (it already loads eh and
//    wave-reduces): MODE2 staging = 2 scalar loads + NW combine (no dots,
//    no shfl, no sigmoid on the critical chain).
//  - dot3 fused into MODE3 staging (nh rows already staged there).
//  - hv carry read from the f16 h-staging LDS in MODE1/MODE2 epilogues
//    (drops the global hv re-read; +<=5e-4/iter f16 rounding).
//  - XCD-bijective block swizzle on gru_mfma grids (1984/64, both %8==0).
//  R10/R12 lesson recorded: co-residency is register-walled at this shape;
//  BM=64 wp-amortization wins.
// ---------------------------------------------------------------------------

#define D_DIM 256
#define NNODE 32
#define NEDGE 992
#define EDGE_ROWS (128 * NEDGE)   // 126976
#define NODE_ROWS (128 * NNODE)   // 4096
#define BM 64
#define XH_OFF 0                  // MODE1: x half [0,512) of 1KB row
#define HH_OFF 512                // MODE1: h half [512,1024)
#define GI_OFF 32768              // MODE2: gi region after the 32KB eh region
#define GI_STR 776                // gi row stride in f16 words (768 + 8 pad)

typedef _Float16 half8 __attribute__((ext_vector_type(8)));
typedef __attribute__((ext_vector_type(4))) float f32x4;

__device__ __forceinline__ float sigf(float x) { return 1.0f / (1.0f + __expf(-x)); }
__device__ __forceinline__ float tanh_fast(float x) { return 2.0f / (1.0f + __expf(-2.0f * x)) - 1.0f; }
__device__ __forceinline__ float dot4(float4 a, float4 b) { return a.x*b.x + a.y*b.y + a.z*b.z + a.w*b.w; }

// Pack Wc[512][768] (rows 0-255 = WihT, 256-511 = WhhT) into MFMA B-fragment
// order, f16.
__global__ __launch_bounds__(64) void pack_w(const float* __restrict__ Wih,
                                             const float* __restrict__ Whh,
                                             _Float16* __restrict__ ph) {
  const int ct = blockIdx.x;   // 0..47
  const int ks = blockIdx.y;   // 0..15
  const int l = threadIdx.x;   // 0..63
  const int col = ct * 16 + (l & 15);
  const int kb = ks * 32 + (l >> 4) * 8;
  const float* src = (kb < 256) ? (Wih + col * 256 + kb) : (Whh + col * 256 + (kb - 256));
  half8 v;
  #pragma unroll
  for (int j = 0; j < 8; ++j) v[j] = (_Float16)src[j];
  *(half8*)(ph + ((ct * 16 + ks) * 64 + l) * 8) = v;
}

// MODE 0: init GRU (x only, h=0).   MODE 1: node iter GRU (K-split h-first).
// MODE 2: edge iter (h-GEMM + NW-combined gi; gSe/gOe precomputed).
// MODE 3: NW = nh @ edge_WihT (f16 out) + fused dot3 (dotA/dotS/dotO).
template <int MODE>
__global__ __launch_bounds__(1024, 4) void gru_mfma(
    const float* __restrict__ xsrc, float* __restrict__ h,
    const _Float16* __restrict__ wp,
    const float* __restrict__ bih, const float* __restrict__ bhh,
    const float* __restrict__ gSe, const float* __restrict__ gOe,
    _Float16* __restrict__ nw,
    const float* __restrict__ wnp, const float* __restrict__ wes,
    const float* __restrict__ weo,
    float* __restrict__ dA, float* __restrict__ dS, float* __restrict__ dO) {
  constexpr int RSTR = (MODE == 1) ? 1024 : 512;
  constexpr int LDSB = (MODE == 1) ? 65536 : (MODE == 2 ? 32768 + BM * GI_STR * 2 : 32768);
  __shared__ __align__(16) unsigned char lds[LDSB];

  const int t = threadIdx.x;
  const int cpx = gridDim.x >> 3;                       // XCD-bijective swizzle
  const int bx = (blockIdx.x & 7) * cpx + (blockIdx.x >> 3);
  const int rb = bx * BM;
  const int srow = t >> 4;       // staging: 16 threads per row
  const int skc = t & 15;
  const int w = t >> 6;          // compute: wave -> within-gate col-tile
  const int l = t & 63;
  const int lq = l >> 4;
  const int lr = l & 15;
  const int swm = (lr & 7) << 4;
  const int swz = (srow & 7) << 4;
  const int rowg = rb + srow;

  if constexpr (MODE == 2) {
    // ---- staging: eh row -> f16 LDS; gs/go scalar loads; NW gather -> gi ----
    const int b = rowg / NEDGE;
    const int e = rowg - b * NEDGE;
    const int si = e / 31;
    const int m = e - si * 31;
    const int ob = (m < si) ? m : (m + 1);
    const float gs = gSe[rowg];
    const float go = gOe[rowg];

    float4 pre[4];
    #pragma unroll
    for (int i = 0; i < 4; ++i)
      pre[i] = *(const float4*)(h + rowg * D_DIM + (i >> 1) * 128 + skc * 8 + (i & 1) * 4);
    #pragma unroll
    for (int c = 0; c < 2; ++c) {
      half8 hh8;
      const float* f1 = (const float*)&pre[c * 2];
      #pragma unroll
      for (int j = 0; j < 8; ++j) hh8[j] = (_Float16)f1[j];
      *(half8*)(&lds[(srow * 512 + c * 256 + skc * 16) ^ swz]) = hh8;
    }
    const _Float16 gsh = (_Float16)gs, goh = (_Float16)go;
    const _Float16* ns = nw + (b * NNODE + si) * 768;
    const _Float16* no_ = nw + (b * NNODE + ob) * 768;
    _Float16* giw = (_Float16*)(lds + GI_OFF) + srow * GI_STR;
    #pragma unroll
    for (int j = 0; j < 6; ++j) {          // cols skc*8 + j*128 (conflict-free)
      const int c0 = skc * 8 + j * 128;
      const half8 a = *(const half8*)(ns + c0);
      const half8 bb = *(const half8*)(no_ + c0);
      half8 g;
      #pragma unroll
      for (int k = 0; k < 8; ++k) g[k] = gsh * a[k] + goh * bb[k];
      *(half8*)(giw + c0) = g;
    }
  } else if constexpr (MODE == 3) {
    // ---- staging: nh rows -> f16 LDS + fused dot3 ----
    float4 xa[4];
    #pragma unroll
    for (int i = 0; i < 4; ++i)
      xa[i] = *(const float4*)(xsrc + rowg * D_DIM + (i >> 1) * 128 + skc * 8 + (i & 1) * 4);
    #pragma unroll
    for (int c = 0; c < 2; ++c) {
      half8 hx;
      const float* f0 = (const float*)&xa[c * 2];
      #pragma unroll
      for (int j = 0; j < 8; ++j) hx[j] = (_Float16)f0[j];
      *(half8*)(&lds[(srow * 512 + c * 256 + skc * 16) ^ swz]) = hx;
    }
    float p1 = 0.f, p2 = 0.f, p3 = 0.f;
    #pragma unroll
    for (int i = 0; i < 4; ++i) {
      const int k0 = (i >> 1) * 128 + skc * 8 + (i & 1) * 4;
      p1 += dot4(xa[i], *(const float4*)(wnp + k0));
      p2 += dot4(xa[i], *(const float4*)(wes + k0));
      p3 += dot4(xa[i], *(const float4*)(weo + k0));
    }
    #pragma unroll
    for (int mm = 1; mm < 16; mm <<= 1) {
      p1 += __shfl_xor(p1, mm, 16);
      p2 += __shfl_xor(p2, mm, 16);
      p3 += __shfl_xor(p3, mm, 16);
    }
    if (skc == 0) { dA[rowg] = p1; dS[rowg] = p2; dO[rowg] = p3; }
  } else if constexpr (MODE == 0) {
    // stage x rows
    #pragma unroll
    for (int c = 0; c < 2; ++c) {
      half8 hx;
      #pragma unroll
      for (int pq = 0; pq < 2; ++pq) {
        const float4 a = *(const float4*)(xsrc + rowg * D_DIM + c * 128 + skc * 8 + pq * 4);
        hx[pq * 4 + 0] = (_Float16)a.x; hx[pq * 4 + 1] = (_Float16)a.y;
        hx[pq * 4 + 2] = (_Float16)a.z; hx[pq * 4 + 3] = (_Float16)a.w;
      }
      *(half8*)(&lds[(srow * 512 + c * 256 + skc * 16) ^ swz]) = hx;
    }
  } else {
    // MODE 1 stage1: h rows (f16), consumed fully
    float4 pre[4];
    #pragma unroll
    for (int i = 0; i < 4; ++i)
      pre[i] = *(const float4*)(h + rowg * D_DIM + (i >> 1) * 128 + skc * 8 + (i & 1) * 4);
    #pragma unroll
    for (int c = 0; c < 2; ++c) {
      half8 hh8;
      const float* f1 = (const float*)&pre[c * 2];
      #pragma unroll
      for (int j = 0; j < 8; ++j) hh8[j] = (_Float16)f1[j];
      *(half8*)(&lds[(srow * RSTR + HH_OFF + c * 256 + skc * 16) ^ swz]) = hh8;
    }
  }

  const f32x4 zz = {0.f, 0.f, 0.f, 0.f};
  f32x4 acc_r[4] = {zz, zz, zz, zz};
  f32x4 acc_z[4] = {zz, zz, zz, zz};
  f32x4 acc_nx[4] = {zz, zz, zz, zz};
  f32x4 acc_nh[4] = {zz, zz, zz, zz};

  auto KS = [&](int hoff, int ksgl, int ksg, f32x4 (&accn)[4]) {
    half8 ah[4];
    #pragma unroll
    for (int rf = 0; rf < 4; ++rf)
      ah[rf] = *(const half8*)(&lds[((rf * 16 + lr) * RSTR + hoff + ksgl * 64 + lq * 16) ^ swm]);
    const half8 br_ = *(const half8*)(wp + (((0 * 16 + w) * 16 + ksg) * 64 + l) * 8);
    const half8 bz_ = *(const half8*)(wp + (((1 * 16 + w) * 16 + ksg) * 64 + l) * 8);
    const half8 bn_ = *(const half8*)(wp + (((2 * 16 + w) * 16 + ksg) * 64 + l) * 8);
    #pragma unroll
    for (int rf = 0; rf < 4; ++rf)
      acc_r[rf] = __builtin_amdgcn_mfma_f32_16x16x32_f16(ah[rf], br_, acc_r[rf], 0, 0, 0);
    #pragma unroll
    for (int rf = 0; rf < 4; ++rf)
      acc_z[rf] = __builtin_amdgcn_mfma_f32_16x16x32_f16(ah[rf], bz_, acc_z[rf], 0, 0, 0);
    #pragma unroll
    for (int rf = 0; rf < 4; ++rf)
      accn[rf] = __builtin_amdgcn_mfma_f32_16x16x32_f16(ah[rf], bn_, accn[rf], 0, 0, 0);
  };

  __syncthreads();

  if constexpr (MODE == 0 || MODE == 3) {
    #pragma unroll
    for (int ksgl = 0; ksgl < 8; ++ksgl) KS(0, ksgl, ksgl, acc_nx);
  } else if constexpr (MODE == 2) {
    #pragma unroll
    for (int ksgl = 0; ksgl < 8; ++ksgl) KS(0, ksgl, 8 + ksgl, acc_nh);
  } else {
    // MODE 1: 96 h-MFMAs, stage x (L2-hot node_msg), 96 x-MFMAs
    #pragma unroll
    for (int ksgl = 0; ksgl < 8; ++ksgl) KS(HH_OFF, ksgl, 8 + ksgl, acc_nh);
    #pragma unroll
    for (int c = 0; c < 2; ++c) {
      half8 hx;
      #pragma unroll
      for (int pq = 0; pq < 2; ++pq) {
        const float4 a = *(const float4*)(xsrc + rowg * D_DIM + c * 128 + skc * 8 + pq * 4);
        hx[pq * 4 + 0] = (_Float16)a.x; hx[pq * 4 + 1] = (_Float16)a.y;
        hx[pq * 4 + 2] = (_Float16)a.z; hx[pq * 4 + 3] = (_Float16)a.w;
      }
      *(half8*)(&lds[(srow * RSTR + XH_OFF + c * 256 + skc * 16) ^ swz]) = hx;
    }
    __syncthreads();
    #pragma unroll
    for (int ksgl = 0; ksgl < 8; ++ksgl) KS(XH_OFF, ksgl, ksgl, acc_nx);
  }

  // ---------------- epilogue ----------------
  const int col = w * 16 + lr;
  if constexpr (MODE == 3) {
    #pragma unroll
    for (int rf = 0; rf < 4; ++rf) {
      #pragma unroll
      for (int q = 0; q < 4; ++q) {
        const int rowl = rf * 16 + lq * 4 + q;
        _Float16* np = nw + (rb + rowl) * 768 + col;
        np[0]   = (_Float16)acc_r[rf][q];
        np[256] = (_Float16)acc_z[rf][q];
        np[512] = (_Float16)acc_nx[rf][q];
      }
    }
    return;
  }
  const float br = bih[col] + bhh[col];
  const float bz = bih[256 + col] + bhh[256 + col];
  const float bnx = bih[512 + col];
  const float bnh = bhh[512 + col];
  #pragma unroll
  for (int rf = 0; rf < 4; ++rf) {
    #pragma unroll
    for (int q = 0; q < 4; ++q) {
      const int rowl = rf * 16 + lq * 4 + q;
      float hv = 0.0f;
      if constexpr (MODE == 1)
        hv = (float)*(const _Float16*)(&lds[(rowl * 1024 + HH_OFF + col * 2) ^ ((rowl & 7) << 4)]);
      if constexpr (MODE == 2)
        hv = (float)*(const _Float16*)(&lds[(rowl * 512 + col * 2) ^ ((rowl & 7) << 4)]);
      float r, z, n;
      if constexpr (MODE == 2) {
        const _Float16* gp = (const _Float16*)(lds + GI_OFF) + rowl * GI_STR + col;
        r = sigf(acc_r[rf][q] + (float)gp[0] + br);
        z = sigf(acc_z[rf][q] + (float)gp[256] + bz);
        n = tanh_fast((float)gp[512] + bnx + r * (acc_nh[rf][q] + bnh));
      } else {
        r = sigf(acc_r[rf][q] + br);
        z = sigf(acc_z[rf][q] + bz);
        n = tanh_fast(acc_nx[rf][q] + bnx + r * (acc_nh[rf][q] + bnh));
      }
      h[(rb + rowl) * D_DIM + col] = (1.0f - z) * n + z * hv;
    }
  }
}

// node_msg[b,n] = sum over 62 incident edges of gN*eh (gN inline), AND
// per out-edge: gSe[e] = sig(dotS[b,sub] + eh.wes[256:]), gOe likewise.
__global__ __launch_bounds__(256) void node_msg_kernel(
    const float* __restrict__ eh, const float* __restrict__ wnp,
    const float* __restrict__ wesb, const float* __restrict__ weob,
    const float* __restrict__ dotA, const float* __restrict__ dotS,
    const float* __restrict__ dotO, float* __restrict__ nmsg,
    float* __restrict__ gSe, float* __restrict__ gOe) {
  __shared__ float sh[3][256];
  const int nr = blockIdx.x;  // 0..4095
  const int b = nr >> 5;
  const int n = nr & 31;
  const int wv = threadIdx.x >> 6;
  const int l = threadIdx.x & 63;
  const int base = b * NEDGE;
  const float4 w1b = ((const float4*)(wnp + 256))[l];
  const float4 wsb = ((const float4*)wesb)[l];
  const float4 wob = ((const float4*)weob)[l];

  float4 acc = {0.f, 0.f, 0.f, 0.f};
  for (int k = wv; k < 62; k += 4) {
    int e, sub;
    if (k < 31) {             // out-edge (n -> *)
      e = base + n * 31 + k;
      sub = n;
    } else {                  // in-edge (i -> n)
      int i = k - 31;
      const int ip = (i < n) ? i : (i + 1);
      e = base + ip * 31 + ((n < ip) ? n : (n - 1));
      sub = ip;
    }
    const float4 ev = ((const float4*)(eh + e * D_DIM))[l];
    float p = dot4(ev, w1b);
    float pS = 0.f, pO = 0.f;
    if (k < 31) { pS = dot4(ev, wsb); pO = dot4(ev, wob); }
    #pragma unroll
    for (int mm = 32; mm > 0; mm >>= 1) {
      p += __shfl_xor(p, mm, 64);
      pS += __shfl_xor(pS, mm, 64);
      pO += __shfl_xor(pO, mm, 64);
    }
    const float gN = sigf(dotA[b * NNODE + sub] + p);
    acc.x += gN * ev.x; acc.y += gN * ev.y; acc.z += gN * ev.z; acc.w += gN * ev.w;
    if (k < 31 && l == 0) {
      const int ob2 = (k < n) ? k : (k + 1);   // obj of edge e = n*31+k
      gSe[e] = sigf(dotS[b * NNODE + n] + pS);
      gOe[e] = sigf(dotO[b * NNODE + ob2] + pO);
    }
  }
  if (wv > 0) *(float4*)(&sh[wv - 1][l * 4]) = acc;
  __syncthreads();
  if (wv == 0) {
    #pragma unroll
    for (int v = 0; v < 3; ++v) {
      const float4 o = *(const float4*)(&sh[v][l * 4]);
      acc.x += o.x; acc.y += o.y; acc.z += o.z; acc.w += o.w;
    }
    *(float4*)(nmsg + nr * D_DIM + l * 4) = acc;
  }
}

extern "C" void kernel_launch(void* const* d_in, const int* in_sizes, int n_in,
                              void* d_out, int out_size, void* d_ws, size_t ws_size,
                              hipStream_t stream) {
  const float* node_latents = (const float*)d_in[0];
  const float* edge_latents = (const float*)d_in[1];
  const float* node_Wih = (const float*)d_in[2];
  const float* node_Whh = (const float*)d_in[3];
  const float* node_bih = (const float*)d_in[4];
  const float* node_bhh = (const float*)d_in[5];
  const float* edge_Wih = (const float*)d_in[6];
  const float* edge_Whh = (const float*)d_in[7];
  const float* edge_bih = (const float*)d_in[8];
  const float* edge_bhh = (const float*)d_in[9];
  const float* w_node_pool = (const float*)d_in[10];
  const float* w_edge_sub = (const float*)d_in[11];
  const float* w_edge_obj = (const float*)d_in[12];

  float* nh = (float*)d_out;
  float* eh = (float*)d_out + NODE_ROWS * D_DIM;

  const int WPLANE = 48 * 16 * 64 * 8;  // 393216 f16 = 768KB
  _Float16* ph_n = (_Float16*)d_ws;
  _Float16* ph_e = ph_n + WPLANE;
  _Float16* NW = ph_e + WPLANE;                    // 4096 x 768 f16 = 6 MB
  float* fw = (float*)(NW + NODE_ROWS * 768);
  float* dotA = fw; fw += NODE_ROWS;
  float* dotS = fw; fw += NODE_ROWS;
  float* dotO = fw; fw += NODE_ROWS;
  float* gSe = fw; fw += EDGE_ROWS;
  float* gOe = fw; fw += EDGE_ROWS;
  float* node_msg = fw; fw += NODE_ROWS * D_DIM;   // total ~12.6 MB

  dim3 pg(48, 16);
  pack_w<<<pg, 64, 0, stream>>>(node_Wih, node_Whh, ph_n);
  pack_w<<<pg, 64, 0, stream>>>(edge_Wih, edge_Whh, ph_e);

  const int EGRID = EDGE_ROWS / BM;  // 1984
  const int NGRID = NODE_ROWS / BM;  // 64

  gru_mfma<0><<<NGRID, 1024, 0, stream>>>(
      node_latents, nh, ph_n, node_bih, node_bhh,
      nullptr, nullptr, nullptr, nullptr, nullptr, nullptr,
      nullptr, nullptr, nullptr);
  gru_mfma<0><<<EGRID, 1024, 0, stream>>>(
      edge_latents, eh, ph_e, edge_bih, edge_bhh,
      nullptr, nullptr, nullptr, nullptr, nullptr, nullptr,
      nullptr, nullptr, nullptr);

  for (int it = 0; it < 3; ++it) {
    // NW + dot3 (reads old nh)
    gru_mfma<3><<<NGRID, 1024, 0, stream>>>(
        nh, nullptr, ph_e, nullptr, nullptr,
        nullptr, nullptr, NW, w_node_pool, w_edge_sub, w_edge_obj,
        dotA, dotS, dotO);
    // node_msg + per-edge gSe/gOe (reads old eh, dots)
    node_msg_kernel<<<NODE_ROWS, 256, 0, stream>>>(
        eh, w_node_pool, w_edge_sub + 256, w_edge_obj + 256,
        dotA, dotS, dotO, node_msg, gSe, gOe);
    // edge GRU in place
    gru_mfma<2><<<EGRID, 1024, 0, stream>>>(
        nullptr, eh, ph_e, edge_bih, edge_bhh,
        gSe, gOe, NW, nullptr, nullptr, nullptr, nullptr, nullptr, nullptr);
    // node GRU in place
    gru_mfma<1><<<NGRID, 1024, 0, stream>>>(
        node_msg, nh, ph_n, node_bih, node_bhh,
        nullptr, nullptr, nullptr, nullptr, nullptr, nullptr,
        nullptr, nullptr, nullptr);
  }
}

// Round 15
// 801.812 us; speedup vs baseline: 1.0024x; 1.0024x over previous
//
#include <hip/hip_runtime.h>

// ---------------------------------------------------------------------------
// Round 14: R11 base + f16 hidden-image staging for the edge GRU.
//  - eh16: f16 row-major copy of edge hidden, written by MODE0-edge/MODE2
//    epilogues (LDS transpose in the freed A-buffer -> coalesced stores).
//    MODE2 staging = plain 16B copy (no f32 load, no cvt, no dots). Guarded
//    by ws_size; f32 fallback path otherwise (template flag F16).
//  - gSe/gOe precomputed in node_msg (split loops: 3-shfl only for the 31
//    out-edges -- fixes the R13 regression).
//  - hv carry from LDS f16 staging (R13-proven, absmax unchanged).
//  - No XCD swizzle (R13 showed it mildly negative here).
// ---------------------------------------------------------------------------

#define D_DIM 256
#define NNODE 32
#define NEDGE 992
#define EDGE_ROWS (128 * NEDGE)   // 126976
#define NODE_ROWS (128 * NNODE)   // 4096
#define BM 64
#define XH_OFF 0                  // MODE1: x half [0,512) of 1KB row
#define HH_OFF 512                // MODE1: h half [512,1024)
#define GI_OFF 32768              // MODE2: gi region after the 32KB A region
#define GI_STR 776                // gi row stride in f16 words (768 + 8 pad)

typedef _Float16 half8 __attribute__((ext_vector_type(8)));
typedef __attribute__((ext_vector_type(4))) float f32x4;

__device__ __forceinline__ float sigf(float x) { return 1.0f / (1.0f + __expf(-x)); }
__device__ __forceinline__ float tanh_fast(float x) { return 2.0f / (1.0f + __expf(-2.0f * x)) - 1.0f; }
__device__ __forceinline__ float dot4(float4 a, float4 b) { return a.x*b.x + a.y*b.y + a.z*b.z + a.w*b.w; }

// Pack Wc[512][768] (rows 0-255 = WihT, 256-511 = WhhT) into MFMA B-fragment
// order, f16.
__global__ __launch_bounds__(64) void pack_w(const float* __restrict__ Wih,
                                             const float* __restrict__ Whh,
                                             _Float16* __restrict__ ph) {
  const int ct = blockIdx.x;   // 0..47
  const int ks = blockIdx.y;   // 0..15
  const int l = threadIdx.x;   // 0..63
  const int col = ct * 16 + (l & 15);
  const int kb = ks * 32 + (l >> 4) * 8;
  const float* src = (kb < 256) ? (Wih + col * 256 + kb) : (Whh + col * 256 + (kb - 256));
  half8 v;
  #pragma unroll
  for (int j = 0; j < 8; ++j) v[j] = (_Float16)src[j];
  *(half8*)(ph + ((ct * 16 + ks) * 64 + l) * 8) = v;
}

// MODE 0: init GRU (x only, h=0); F16 -> also emit h16o image.
// MODE 1: node iter GRU (K-split h-first, LDS hv carry).
// MODE 2: edge iter; F16 -> stage from h16i image, emit h16o; else f32 stage.
// MODE 3: NW = nh @ edge_WihT (f16 out to h16o).
template <int MODE, bool F16>
__global__ __launch_bounds__(1024, 4) void gru_mfma(
    const float* __restrict__ xsrc, float* __restrict__ h,
    const _Float16* __restrict__ wp,
    const float* __restrict__ bih, const float* __restrict__ bhh,
    const float* __restrict__ gSe, const float* __restrict__ gOe,
    const _Float16* __restrict__ nw,
    const _Float16* __restrict__ h16i, _Float16* __restrict__ h16o) {
  constexpr int RSTR = (MODE == 1) ? 1024 : 512;
  constexpr int LDSB = (MODE == 1) ? 65536 : (MODE == 2 ? 32768 + BM * GI_STR * 2 : 32768);
  __shared__ __align__(16) unsigned char lds[LDSB];

  const int t = threadIdx.x;
  const int rb = blockIdx.x * BM;
  const int srow = t >> 4;       // staging: 16 threads per row
  const int skc = t & 15;
  const int w = t >> 6;          // compute: wave -> within-gate col-tile
  const int l = t & 63;
  const int lq = l >> 4;
  const int lr = l & 15;
  const int swm = (lr & 7) << 4;
  const int swz = (srow & 7) << 4;
  const int rowg = rb + srow;

  if constexpr (MODE == 2) {
    // ---- A staging ----
    if constexpr (F16) {
      // pure copy of the f16 hidden image (L3-resident)
      #pragma unroll
      for (int p = 0; p < 2; ++p) {
        const int c = t + p * 1024;
        const int row = c >> 5;
        const int kc = c & 31;
        const uint4 v = *(const uint4*)(h16i + (rb + row) * 256 + kc * 8);
        *(uint4*)(&lds[(row * 512 + kc * 16) ^ ((row & 7) << 4)]) = v;
      }
    } else {
      float4 pre[4];
      #pragma unroll
      for (int i = 0; i < 4; ++i)
        pre[i] = *(const float4*)(h + rowg * D_DIM + (i >> 1) * 128 + skc * 8 + (i & 1) * 4);
      #pragma unroll
      for (int c = 0; c < 2; ++c) {
        half8 hh8;
        const float* f1 = (const float*)&pre[c * 2];
        #pragma unroll
        for (int j = 0; j < 8; ++j) hh8[j] = (_Float16)f1[j];
        *(half8*)(&lds[(srow * 512 + c * 256 + skc * 16) ^ swz]) = hh8;
      }
    }
    // ---- gates (precomputed) + NW gather -> gi ----
    const int b = rowg / NEDGE;
    const int e = rowg - b * NEDGE;
    const int si = e / 31;
    const int m = e - si * 31;
    const int ob = (m < si) ? m : (m + 1);
    const _Float16 gsh = (_Float16)gSe[rowg];
    const _Float16 goh = (_Float16)gOe[rowg];
    const _Float16* ns = nw + (b * NNODE + si) * 768;
    const _Float16* no_ = nw + (b * NNODE + ob) * 768;
    _Float16* giw = (_Float16*)(lds + GI_OFF) + srow * GI_STR;
    #pragma unroll
    for (int j = 0; j < 6; ++j) {          // cols skc*8 + j*128 (conflict-free)
      const int c0 = skc * 8 + j * 128;
      const half8 a = *(const half8*)(ns + c0);
      const half8 bb = *(const half8*)(no_ + c0);
      half8 g;
      #pragma unroll
      for (int k = 0; k < 8; ++k) g[k] = gsh * a[k] + goh * bb[k];
      *(half8*)(giw + c0) = g;
    }
  } else if constexpr (MODE == 0 || MODE == 3) {
    // stage x rows (f32 -> f16)
    #pragma unroll
    for (int c = 0; c < 2; ++c) {
      half8 hx;
      #pragma unroll
      for (int pq = 0; pq < 2; ++pq) {
        const float4 a = *(const float4*)(xsrc + rowg * D_DIM + c * 128 + skc * 8 + pq * 4);
        hx[pq * 4 + 0] = (_Float16)a.x; hx[pq * 4 + 1] = (_Float16)a.y;
        hx[pq * 4 + 2] = (_Float16)a.z; hx[pq * 4 + 3] = (_Float16)a.w;
      }
      *(half8*)(&lds[(srow * 512 + c * 256 + skc * 16) ^ swz]) = hx;
    }
  } else {
    // MODE 1 stage1: h rows (f16), consumed fully
    float4 pre[4];
    #pragma unroll
    for (int i = 0; i < 4; ++i)
      pre[i] = *(const float4*)(h + rowg * D_DIM + (i >> 1) * 128 + skc * 8 + (i & 1) * 4);
    #pragma unroll
    for (int c = 0; c < 2; ++c) {
      half8 hh8;
      const float* f1 = (const float*)&pre[c * 2];
      #pragma unroll
      for (int j = 0; j < 8; ++j) hh8[j] = (_Float16)f1[j];
      *(half8*)(&lds[(srow * RSTR + HH_OFF + c * 256 + skc * 16) ^ swz]) = hh8;
    }
  }

  const f32x4 zz = {0.f, 0.f, 0.f, 0.f};
  f32x4 acc_r[4] = {zz, zz, zz, zz};
  f32x4 acc_z[4] = {zz, zz, zz, zz};
  f32x4 acc_nx[4] = {zz, zz, zz, zz};
  f32x4 acc_nh[4] = {zz, zz, zz, zz};

  auto KS = [&](int hoff, int ksgl, int ksg, f32x4 (&accn)[4]) {
    half8 ah[4];
    #pragma unroll
    for (int rf = 0; rf < 4; ++rf)
      ah[rf] = *(const half8*)(&lds[((rf * 16 + lr) * RSTR + hoff + ksgl * 64 + lq * 16) ^ swm]);
    const half8 br_ = *(const half8*)(wp + (((0 * 16 + w) * 16 + ksg) * 64 + l) * 8);
    const half8 bz_ = *(const half8*)(wp + (((1 * 16 + w) * 16 + ksg) * 64 + l) * 8);
    const half8 bn_ = *(const half8*)(wp + (((2 * 16 + w) * 16 + ksg) * 64 + l) * 8);
    #pragma unroll
    for (int rf = 0; rf < 4; ++rf)
      acc_r[rf] = __builtin_amdgcn_mfma_f32_16x16x32_f16(ah[rf], br_, acc_r[rf], 0, 0, 0);
    #pragma unroll
    for (int rf = 0; rf < 4; ++rf)
      acc_z[rf] = __builtin_amdgcn_mfma_f32_16x16x32_f16(ah[rf], bz_, acc_z[rf], 0, 0, 0);
    #pragma unroll
    for (int rf = 0; rf < 4; ++rf)
      accn[rf] = __builtin_amdgcn_mfma_f32_16x16x32_f16(ah[rf], bn_, accn[rf], 0, 0, 0);
  };

  __syncthreads();

  if constexpr (MODE == 0 || MODE == 3) {
    #pragma unroll
    for (int ksgl = 0; ksgl < 8; ++ksgl) KS(0, ksgl, ksgl, acc_nx);
  } else if constexpr (MODE == 2) {
    #pragma unroll
    for (int ksgl = 0; ksgl < 8; ++ksgl) KS(0, ksgl, 8 + ksgl, acc_nh);
  } else {
    // MODE 1: 96 h-MFMAs, stage x (L2-hot node_msg), 96 x-MFMAs
    #pragma unroll
    for (int ksgl = 0; ksgl < 8; ++ksgl) KS(HH_OFF, ksgl, 8 + ksgl, acc_nh);
    #pragma unroll
    for (int c = 0; c < 2; ++c) {
      half8 hx;
      #pragma unroll
      for (int pq = 0; pq < 2; ++pq) {
        const float4 a = *(const float4*)(xsrc + rowg * D_DIM + c * 128 + skc * 8 + pq * 4);
        hx[pq * 4 + 0] = (_Float16)a.x; hx[pq * 4 + 1] = (_Float16)a.y;
        hx[pq * 4 + 2] = (_Float16)a.z; hx[pq * 4 + 3] = (_Float16)a.w;
      }
      *(half8*)(&lds[(srow * RSTR + XH_OFF + c * 256 + skc * 16) ^ swz]) = hx;
    }
    __syncthreads();
    #pragma unroll
    for (int ksgl = 0; ksgl < 8; ++ksgl) KS(XH_OFF, ksgl, ksgl, acc_nx);
  }

  // ---------------- epilogue ----------------
  const int col = w * 16 + lr;
  if constexpr (MODE == 3) {
    #pragma unroll
    for (int rf = 0; rf < 4; ++rf) {
      #pragma unroll
      for (int q = 0; q < 4; ++q) {
        const int rowl = rf * 16 + lq * 4 + q;
        _Float16* np = h16o + (rb + rowl) * 768 + col;
        np[0]   = (_Float16)acc_r[rf][q];
        np[256] = (_Float16)acc_z[rf][q];
        np[512] = (_Float16)acc_nx[rf][q];
      }
    }
    return;
  }
  const float br = bih[col] + bhh[col];
  const float bz = bih[256 + col] + bhh[256 + col];
  const float bnx = bih[512 + col];
  const float bnh = bhh[512 + col];
  _Float16 sv[16];
  #pragma unroll
  for (int rf = 0; rf < 4; ++rf) {
    #pragma unroll
    for (int q = 0; q < 4; ++q) {
      const int rowl = rf * 16 + lq * 4 + q;
      float hv = 0.0f;
      if constexpr (MODE == 1)
        hv = (float)*(const _Float16*)(&lds[(rowl * 1024 + HH_OFF + col * 2) ^ ((rowl & 7) << 4)]);
      if constexpr (MODE == 2)
        hv = (float)*(const _Float16*)(&lds[(rowl * 512 + col * 2) ^ ((rowl & 7) << 4)]);
      float r, z, n;
      if constexpr (MODE == 2) {
        const _Float16* gp = (const _Float16*)(lds + GI_OFF) + rowl * GI_STR + col;
        r = sigf(acc_r[rf][q] + (float)gp[0] + br);
        z = sigf(acc_z[rf][q] + (float)gp[256] + bz);
        n = tanh_fast((float)gp[512] + bnx + r * (acc_nh[rf][q] + bnh));
      } else {
        r = sigf(acc_r[rf][q] + br);
        z = sigf(acc_z[rf][q] + bz);
        n = tanh_fast(acc_nx[rf][q] + bnx + r * (acc_nh[rf][q] + bnh));
      }
      const float out = (1.0f - z) * n + z * hv;
      h[(rb + rowl) * D_DIM + col] = out;
      sv[rf * 4 + q] = (_Float16)out;
    }
  }
  // ---- f16 image writeback (LDS transpose in the A region) ----
  if constexpr (F16 && (MODE == 0 || MODE == 2)) {
    __syncthreads();  // all A-LDS / gi reads done
    #pragma unroll
    for (int rf = 0; rf < 4; ++rf) {
      #pragma unroll
      for (int q = 0; q < 4; ++q) {
        const int rowl = rf * 16 + lq * 4 + q;
        *(_Float16*)(&lds[(rowl * 512 + col * 2) ^ ((rowl & 7) << 4)]) = sv[rf * 4 + q];
      }
    }
    __syncthreads();
    #pragma unroll
    for (int p = 0; p < 2; ++p) {
      const int c = t + p * 1024;
      const int row = c >> 5;
      const int kc = c & 31;
      *(uint4*)(h16o + (rb + row) * 256 + kc * 8) =
          *(const uint4*)(&lds[(row * 512 + kc * 16) ^ ((row & 7) << 4)]);
    }
  }
}

// per node row: dotA = nh.wnp[0:256], dotS = nh.wes[0:256], dotO = nh.weo[0:256]
__global__ __launch_bounds__(256) void dot3_kernel(
    const float* __restrict__ nh, const float* __restrict__ wnp,
    const float* __restrict__ wes, const float* __restrict__ weo,
    float* __restrict__ dA, float* __restrict__ dS, float* __restrict__ dO) {
  const int r = blockIdx.x * 4 + (threadIdx.x >> 6);
  const int l = threadIdx.x & 63;
  const float4 v = ((const float4*)(nh + r * D_DIM))[l];
  float p1 = dot4(v, ((const float4*)wnp)[l]);
  float p2 = dot4(v, ((const float4*)wes)[l]);
  float p3 = dot4(v, ((const float4*)weo)[l]);
  #pragma unroll
  for (int mm = 32; mm > 0; mm >>= 1) {
    p1 += __shfl_xor(p1, mm, 64);
    p2 += __shfl_xor(p2, mm, 64);
    p3 += __shfl_xor(p3, mm, 64);
  }
  if (l == 0) { dA[r] = p1; dS[r] = p2; dO[r] = p3; }
}

// node_msg[b,n] = sum over 62 incident edges of gN*eh (gN inline).
// Out-edge loop additionally emits gSe/gOe (covers every edge exactly once).
__global__ __launch_bounds__(256) void node_msg_kernel(
    const float* __restrict__ eh, const float* __restrict__ wnp,
    const float* __restrict__ wesb, const float* __restrict__ weob,
    const float* __restrict__ dotA, const float* __restrict__ dotS,
    const float* __restrict__ dotO, float* __restrict__ nmsg,
    float* __restrict__ gSe, float* __restrict__ gOe) {
  __shared__ float sh[3][256];
  const int nr = blockIdx.x;  // 0..4095
  const int b = nr >> 5;
  const int n = nr & 31;
  const int wv = threadIdx.x >> 6;
  const int l = threadIdx.x & 63;
  const int base = b * NEDGE;
  const float4 w1b = ((const float4*)(wnp + 256))[l];
  const float4 wsb = ((const float4*)wesb)[l];
  const float4 wob = ((const float4*)weob)[l];

  float4 acc = {0.f, 0.f, 0.f, 0.f};
  // out-edges (n -> *): gN contribution + gSe/gOe emission
  for (int k = wv; k < 31; k += 4) {
    const int e = base + n * 31 + k;
    const float4 ev = ((const float4*)(eh + e * D_DIM))[l];
    float p = dot4(ev, w1b);
    float pS = dot4(ev, wsb);
    float pO = dot4(ev, wob);
    #pragma unroll
    for (int mm = 32; mm > 0; mm >>= 1) {
      p += __shfl_xor(p, mm, 64);
      pS += __shfl_xor(pS, mm, 64);
      pO += __shfl_xor(pO, mm, 64);
    }
    const float gN = sigf(dotA[b * NNODE + n] + p);
    acc.x += gN * ev.x; acc.y += gN * ev.y; acc.z += gN * ev.z; acc.w += gN * ev.w;
    if (l == 0) {
      const int ob2 = (k < n) ? k : (k + 1);
      gSe[e] = sigf(dotS[b * NNODE + n] + pS);
      gOe[e] = sigf(dotO[b * NNODE + ob2] + pO);
    }
  }
  // in-edges (i -> n): gN contribution only
  for (int i = wv; i < 31; i += 4) {
    const int ip = (i < n) ? i : (i + 1);
    const int e = base + ip * 31 + ((n < ip) ? n : (n - 1));
    const float4 ev = ((const float4*)(eh + e * D_DIM))[l];
    float p = dot4(ev, w1b);
    #pragma unroll
    for (int mm = 32; mm > 0; mm >>= 1) p += __shfl_xor(p, mm, 64);
    const float gN = sigf(dotA[b * NNODE + ip] + p);
    acc.x += gN * ev.x; acc.y += gN * ev.y; acc.z += gN * ev.z; acc.w += gN * ev.w;
  }
  if (wv > 0) *(float4*)(&sh[wv - 1][l * 4]) = acc;
  __syncthreads();
  if (wv == 0) {
    #pragma unroll
    for (int v = 0; v < 3; ++v) {
      const float4 o = *(const float4*)(&sh[v][l * 4]);
      acc.x += o.x; acc.y += o.y; acc.z += o.z; acc.w += o.w;
    }
    *(float4*)(nmsg + nr * D_DIM + l * 4) = acc;
  }
}

extern "C" void kernel_launch(void* const* d_in, const int* in_sizes, int n_in,
                              void* d_out, int out_size, void* d_ws, size_t ws_size,
                              hipStream_t stream) {
  const float* node_latents = (const float*)d_in[0];
  const float* edge_latents = (const float*)d_in[1];
  const float* node_Wih = (const float*)d_in[2];
  const float* node_Whh = (const float*)d_in[3];
  const float* node_bih = (const float*)d_in[4];
  const float* node_bhh = (const float*)d_in[5];
  const float* edge_Wih = (const float*)d_in[6];
  const float* edge_Whh = (const float*)d_in[7];
  const float* edge_bih = (const float*)d_in[8];
  const float* edge_bhh = (const float*)d_in[9];
  const float* w_node_pool = (const float*)d_in[10];
  const float* w_edge_sub = (const float*)d_in[11];
  const float* w_edge_obj = (const float*)d_in[12];

  float* nh = (float*)d_out;
  float* eh = (float*)d_out + NODE_ROWS * D_DIM;

  const int WPLANE = 48 * 16 * 64 * 8;  // 393216 f16 = 768KB
  _Float16* ph_n = (_Float16*)d_ws;
  _Float16* ph_e = ph_n + WPLANE;
  _Float16* NW = ph_e + WPLANE;                    // 4096 x 768 f16 = 6 MB
  float* fw = (float*)(NW + NODE_ROWS * 768);
  float* dotA = fw; fw += NODE_ROWS;
  float* dotS = fw; fw += NODE_ROWS;
  float* dotO = fw; fw += NODE_ROWS;
  float* gSe = fw; fw += EDGE_ROWS;
  float* gOe = fw; fw += EDGE_ROWS;
  float* node_msg = fw; fw += NODE_ROWS * D_DIM;   // ~12.6 MB so far
  _Float16* eh16 = (_Float16*)fw;                  // +65 MB if it fits
  const size_t need = ((size_t)((char*)fw - (char*)d_ws)) +
                      (size_t)EDGE_ROWS * D_DIM * sizeof(_Float16);
  const bool F16OK = ws_size >= need;

  dim3 pg(48, 16);
  pack_w<<<pg, 64, 0, stream>>>(node_Wih, node_Whh, ph_n);
  pack_w<<<pg, 64, 0, stream>>>(edge_Wih, edge_Whh, ph_e);

  const int EGRID = EDGE_ROWS / BM;  // 1984
  const int NGRID = NODE_ROWS / BM;  // 64

  gru_mfma<0, false><<<NGRID, 1024, 0, stream>>>(
      node_latents, nh, ph_n, node_bih, node_bhh,
      nullptr, nullptr, nullptr, nullptr, nullptr);
  if (F16OK)
    gru_mfma<0, true><<<EGRID, 1024, 0, stream>>>(
        edge_latents, eh, ph_e, edge_bih, edge_bhh,
        nullptr, nullptr, nullptr, nullptr, eh16);
  else
    gru_mfma<0, false><<<EGRID, 1024, 0, stream>>>(
        edge_latents, eh, ph_e, edge_bih, edge_bhh,
        nullptr, nullptr, nullptr, nullptr, nullptr);

  for (int it = 0; it < 3; ++it) {
    dot3_kernel<<<NODE_ROWS / 4, 256, 0, stream>>>(nh, w_node_pool, w_edge_sub,
                                                   w_edge_obj, dotA, dotS, dotO);
    gru_mfma<3, false><<<NGRID, 1024, 0, stream>>>(
        nh, nullptr, ph_e, nullptr, nullptr,
        nullptr, nullptr, nullptr, nullptr, NW);
    node_msg_kernel<<<NODE_ROWS, 256, 0, stream>>>(
        eh, w_node_pool, w_edge_sub + 256, w_edge_obj + 256,
        dotA, dotS, dotO, node_msg, gSe, gOe);
    if (F16OK)
      gru_mfma<2, true><<<EGRID, 1024, 0, stream>>>(
          nullptr, eh, ph_e, edge_bih, edge_bhh,
          gSe, gOe, NW, eh16, eh16);
    else
      gru_mfma<2, false><<<EGRID, 1024, 0, stream>>>(
          nullptr, eh, ph_e, edge_bih, edge_bhh,
          gSe, gOe, NW, nullptr, nullptr);
    gru_mfma<1, false><<<NGRID, 1024, 0, stream>>>(
        node_msg, nh, ph_n, node_bih, node_bhh,
        nullptr, nullptr, nullptr, nullptr, nullptr);
  }
}

// Round 16
// 715.608 us; speedup vs baseline: 1.1232x; 1.1205x over previous
//
#include <hip/hip_runtime.h>

// ---------------------------------------------------------------------------
// Round 15: R11 math/structure verbatim (best: 744us) + dispatch fusion only.
//  R12/R13/R14 lessons: co-residency is register-walled; MODE2's staging
//  chain is NOT the limiter (gate-precompute and f16-image staging both
//  null); eh16 image writeback costs more than it saves. So: no structural
//  changes. Harvest launch/serialization slack instead:
//   - gru_init: edge-init + node-init in ONE 2048-block dispatch.
//   - gru_nw:   MODE3 (NW = nh @ edge_WihT) with dot3 fused into staging
//               (R13-verified piece).
//   - gru_iter: MODE2 (1984 blocks) + MODE1 (64 blocks) in ONE dispatch --
//               no mutual dependency; MODE1 rides the MODE2 tail.
//  19 launches -> 12.
// ---------------------------------------------------------------------------

#define D_DIM 256
#define NNODE 32
#define NEDGE 992
#define EDGE_ROWS (128 * NEDGE)   // 126976
#define NODE_ROWS (128 * NNODE)   // 4096
#define BM 64
#define EGRID (EDGE_ROWS / BM)    // 1984
#define NGRID (NODE_ROWS / BM)    // 64
#define GI_OFF 32768              // MODE2: gi region after the 32KB A region
#define GI_STR 776                // gi row stride in f16 words (768 + 8 pad)

typedef _Float16 half8 __attribute__((ext_vector_type(8)));
typedef __attribute__((ext_vector_type(4))) float f32x4;

__device__ __forceinline__ float sigf(float x) { return 1.0f / (1.0f + __expf(-x)); }
__device__ __forceinline__ float tanh_fast(float x) { return 2.0f / (1.0f + __expf(-2.0f * x)) - 1.0f; }
__device__ __forceinline__ float dot4(float4 a, float4 b) { return a.x*b.x + a.y*b.y + a.z*b.z + a.w*b.w; }

// Pack Wc[512][768] (rows 0-255 = WihT, 256-511 = WhhT) into MFMA B-fragment
// order, f16.
__global__ __launch_bounds__(64) void pack_w(const float* __restrict__ Wih,
                                             const float* __restrict__ Whh,
                                             _Float16* __restrict__ ph) {
  const int ct = blockIdx.x;   // 0..47
  const int ks = blockIdx.y;   // 0..15
  const int l = threadIdx.x;   // 0..63
  const int col = ct * 16 + (l & 15);
  const int kb = ks * 32 + (l >> 4) * 8;
  const float* src = (kb < 256) ? (Wih + col * 256 + kb) : (Whh + col * 256 + (kb - 256));
  half8 v;
  #pragma unroll
  for (int j = 0; j < 8; ++j) v[j] = (_Float16)src[j];
  *(half8*)(ph + ((ct * 16 + ks) * 64 + l) * 8) = v;
}

// ---- INIT GRU (h=0): edge blocks [0,EGRID), node blocks [EGRID,EGRID+NGRID) ----
__global__ __launch_bounds__(1024, 4) void gru_init(
    const float* __restrict__ xe, const float* __restrict__ xn,
    float* __restrict__ he, float* __restrict__ hn,
    const _Float16* __restrict__ wpe, const _Float16* __restrict__ wpn,
    const float* __restrict__ ebih, const float* __restrict__ ebhh,
    const float* __restrict__ nbih, const float* __restrict__ nbhh) {
  __shared__ __align__(16) unsigned char lds[32768];
  const bool edge = blockIdx.x < EGRID;
  const int bx = edge ? blockIdx.x : (blockIdx.x - EGRID);
  const float* xsrc = edge ? xe : xn;
  float* h = edge ? he : hn;
  const _Float16* wp = edge ? wpe : wpn;
  const float* bih = edge ? ebih : nbih;
  const float* bhh = edge ? ebhh : nbhh;

  const int t = threadIdx.x;
  const int rb = bx * BM;
  const int srow = t >> 4;
  const int skc = t & 15;
  const int w = t >> 6;
  const int l = t & 63;
  const int lq = l >> 4;
  const int lr = l & 15;
  const int swm = (lr & 7) << 4;
  const int swz = (srow & 7) << 4;
  const int rowg = rb + srow;

  #pragma unroll
  for (int c = 0; c < 2; ++c) {
    half8 hx;
    #pragma unroll
    for (int pq = 0; pq < 2; ++pq) {
      const float4 a = *(const float4*)(xsrc + rowg * D_DIM + c * 128 + skc * 8 + pq * 4);
      hx[pq * 4 + 0] = (_Float16)a.x; hx[pq * 4 + 1] = (_Float16)a.y;
      hx[pq * 4 + 2] = (_Float16)a.z; hx[pq * 4 + 3] = (_Float16)a.w;
    }
    *(half8*)(&lds[(srow * 512 + c * 256 + skc * 16) ^ swz]) = hx;
  }
  __syncthreads();

  const f32x4 zz = {0.f, 0.f, 0.f, 0.f};
  f32x4 acc_r[4] = {zz, zz, zz, zz};
  f32x4 acc_z[4] = {zz, zz, zz, zz};
  f32x4 acc_nx[4] = {zz, zz, zz, zz};

  #pragma unroll
  for (int ksg = 0; ksg < 8; ++ksg) {
    half8 ah[4];
    #pragma unroll
    for (int rf = 0; rf < 4; ++rf)
      ah[rf] = *(const half8*)(&lds[((rf * 16 + lr) * 512 + ksg * 64 + lq * 16) ^ swm]);
    const half8 br_ = *(const half8*)(wp + (((0 * 16 + w) * 16 + ksg) * 64 + l) * 8);
    const half8 bz_ = *(const half8*)(wp + (((1 * 16 + w) * 16 + ksg) * 64 + l) * 8);
    const half8 bn_ = *(const half8*)(wp + (((2 * 16 + w) * 16 + ksg) * 64 + l) * 8);
    #pragma unroll
    for (int rf = 0; rf < 4; ++rf)
      acc_r[rf] = __builtin_amdgcn_mfma_f32_16x16x32_f16(ah[rf], br_, acc_r[rf], 0, 0, 0);
    #pragma unroll
    for (int rf = 0; rf < 4; ++rf)
      acc_z[rf] = __builtin_amdgcn_mfma_f32_16x16x32_f16(ah[rf], bz_, acc_z[rf], 0, 0, 0);
    #pragma unroll
    for (int rf = 0; rf < 4; ++rf)
      acc_nx[rf] = __builtin_amdgcn_mfma_f32_16x16x32_f16(ah[rf], bn_, acc_nx[rf], 0, 0, 0);
  }

  const int col = w * 16 + lr;
  const float br = bih[col] + bhh[col];
  const float bz = bih[256 + col] + bhh[256 + col];
  const float bnx = bih[512 + col];
  const float bnh = bhh[512 + col];
  #pragma unroll
  for (int rf = 0; rf < 4; ++rf) {
    #pragma unroll
    for (int q = 0; q < 4; ++q) {
      const int rowl = rf * 16 + lq * 4 + q;
      const float r = sigf(acc_r[rf][q] + br);
      const float z = sigf(acc_z[rf][q] + bz);
      const float n = tanh_fast(acc_nx[rf][q] + bnx + r * bnh);
      h[(rb + rowl) * D_DIM + col] = (1.0f - z) * n;
    }
  }
}

// ---- NW = nh @ edge_WihT (f16 out) with dot3 fused into staging ----
__global__ __launch_bounds__(1024, 4) void gru_nw(
    const float* __restrict__ nh, const _Float16* __restrict__ wp,
    _Float16* __restrict__ nw,
    const float* __restrict__ wnp, const float* __restrict__ wes,
    const float* __restrict__ weo,
    float* __restrict__ dA, float* __restrict__ dS, float* __restrict__ dO) {
  __shared__ __align__(16) unsigned char lds[32768];
  const int t = threadIdx.x;
  const int rb = blockIdx.x * BM;
  const int srow = t >> 4;
  const int skc = t & 15;
  const int w = t >> 6;
  const int l = t & 63;
  const int lq = l >> 4;
  const int lr = l & 15;
  const int swm = (lr & 7) << 4;
  const int swz = (srow & 7) << 4;
  const int rowg = rb + srow;

  float4 xa[4];
  #pragma unroll
  for (int i = 0; i < 4; ++i)
    xa[i] = *(const float4*)(nh + rowg * D_DIM + (i >> 1) * 128 + skc * 8 + (i & 1) * 4);
  #pragma unroll
  for (int c = 0; c < 2; ++c) {
    half8 hx;
    const float* f0 = (const float*)&xa[c * 2];
    #pragma unroll
    for (int j = 0; j < 8; ++j) hx[j] = (_Float16)f0[j];
    *(half8*)(&lds[(srow * 512 + c * 256 + skc * 16) ^ swz]) = hx;
  }
  float p1 = 0.f, p2 = 0.f, p3 = 0.f;
  #pragma unroll
  for (int i = 0; i < 4; ++i) {
    const int k0 = (i >> 1) * 128 + skc * 8 + (i & 1) * 4;
    p1 += dot4(xa[i], *(const float4*)(wnp + k0));
    p2 += dot4(xa[i], *(const float4*)(wes + k0));
    p3 += dot4(xa[i], *(const float4*)(weo + k0));
  }
  #pragma unroll
  for (int mm = 1; mm < 16; mm <<= 1) {
    p1 += __shfl_xor(p1, mm, 16);
    p2 += __shfl_xor(p2, mm, 16);
    p3 += __shfl_xor(p3, mm, 16);
  }
  if (skc == 0) { dA[rowg] = p1; dS[rowg] = p2; dO[rowg] = p3; }
  __syncthreads();

  const f32x4 zz = {0.f, 0.f, 0.f, 0.f};
  f32x4 acc_r[4] = {zz, zz, zz, zz};
  f32x4 acc_z[4] = {zz, zz, zz, zz};
  f32x4 acc_nx[4] = {zz, zz, zz, zz};

  #pragma unroll
  for (int ksg = 0; ksg < 8; ++ksg) {
    half8 ah[4];
    #pragma unroll
    for (int rf = 0; rf < 4; ++rf)
      ah[rf] = *(const half8*)(&lds[((rf * 16 + lr) * 512 + ksg * 64 + lq * 16) ^ swm]);
    const half8 br_ = *(const half8*)(wp + (((0 * 16 + w) * 16 + ksg) * 64 + l) * 8);
    const half8 bz_ = *(const half8*)(wp + (((1 * 16 + w) * 16 + ksg) * 64 + l) * 8);
    const half8 bn_ = *(const half8*)(wp + (((2 * 16 + w) * 16 + ksg) * 64 + l) * 8);
    #pragma unroll
    for (int rf = 0; rf < 4; ++rf)
      acc_r[rf] = __builtin_amdgcn_mfma_f32_16x16x32_f16(ah[rf], br_, acc_r[rf], 0, 0, 0);
    #pragma unroll
    for (int rf = 0; rf < 4; ++rf)
      acc_z[rf] = __builtin_amdgcn_mfma_f32_16x16x32_f16(ah[rf], bz_, acc_z[rf], 0, 0, 0);
    #pragma unroll
    for (int rf = 0; rf < 4; ++rf)
      acc_nx[rf] = __builtin_amdgcn_mfma_f32_16x16x32_f16(ah[rf], bn_, acc_nx[rf], 0, 0, 0);
  }

  const int col = w * 16 + lr;
  #pragma unroll
  for (int rf = 0; rf < 4; ++rf) {
    #pragma unroll
    for (int q = 0; q < 4; ++q) {
      const int rowl = rf * 16 + lq * 4 + q;
      _Float16* np = nw + (rb + rowl) * 768 + col;
      np[0]   = (_Float16)acc_r[rf][q];
      np[256] = (_Float16)acc_z[rf][q];
      np[512] = (_Float16)acc_nx[rf][q];
    }
  }
}

// ---- fused iteration GRU: MODE2 (edge) blocks [0,EGRID), MODE1 (node) rest ----
__global__ __launch_bounds__(1024, 4) void gru_iter(
    float* __restrict__ eh, float* __restrict__ nh,
    const float* __restrict__ nmsg,
    const _Float16* __restrict__ wpe, const _Float16* __restrict__ wpn,
    const float* __restrict__ ebih, const float* __restrict__ ebhh,
    const float* __restrict__ nbih, const float* __restrict__ nbhh,
    const float* __restrict__ wesb, const float* __restrict__ weob,
    const float* __restrict__ dotS, const float* __restrict__ dotO,
    const _Float16* __restrict__ nw) {
  __shared__ __align__(16) unsigned char lds[32768 + BM * GI_STR * 2];  // 132KB

  const int t = threadIdx.x;
  const int srow = t >> 4;
  const int skc = t & 15;
  const int w = t >> 6;
  const int l = t & 63;
  const int lq = l >> 4;
  const int lr = l & 15;
  const int swm = (lr & 7) << 4;
  const int swz = (srow & 7) << 4;

  const f32x4 zz = {0.f, 0.f, 0.f, 0.f};
  f32x4 acc_r[4] = {zz, zz, zz, zz};
  f32x4 acc_z[4] = {zz, zz, zz, zz};
  f32x4 acc_nx[4] = {zz, zz, zz, zz};
  f32x4 acc_nh[4] = {zz, zz, zz, zz};

  if (blockIdx.x < EGRID) {
    // ================= MODE 2: edge GRU =================
    const int rb = blockIdx.x * BM;
    const int rowg = rb + srow;
    const int b = rowg / NEDGE;
    const int e = rowg - b * NEDGE;
    const int si = e / 31;
    const int m = e - si * 31;
    const int ob = (m < si) ? m : (m + 1);

    // stage eh (f32 -> f16 LDS) + gate dots
    float4 pre[4];
    #pragma unroll
    for (int i = 0; i < 4; ++i)
      pre[i] = *(const float4*)(eh + rowg * D_DIM + (i >> 1) * 128 + skc * 8 + (i & 1) * 4);
    #pragma unroll
    for (int c = 0; c < 2; ++c) {
      half8 hh8;
      const float* f1 = (const float*)&pre[c * 2];
      #pragma unroll
      for (int j = 0; j < 8; ++j) hh8[j] = (_Float16)f1[j];
      *(half8*)(&lds[(srow * 512 + c * 256 + skc * 16) ^ swz]) = hh8;
    }
    float pS = 0.f, pO = 0.f;
    #pragma unroll
    for (int i = 0; i < 4; ++i) {
      const int k0 = (i >> 1) * 128 + skc * 8 + (i & 1) * 4;
      pS += dot4(pre[i], *(const float4*)(wesb + k0));
      pO += dot4(pre[i], *(const float4*)(weob + k0));
    }
    #pragma unroll
    for (int mm = 1; mm < 16; mm <<= 1) {
      pS += __shfl_xor(pS, mm, 16);
      pO += __shfl_xor(pO, mm, 16);
    }
    const float gs = sigf(dotS[b * NNODE + si] + pS);
    const float go = sigf(dotO[b * NNODE + ob] + pO);
    const _Float16 gsh = (_Float16)gs, goh = (_Float16)go;
    const _Float16* ns = nw + (b * NNODE + si) * 768;
    const _Float16* no_ = nw + (b * NNODE + ob) * 768;
    _Float16* giw = (_Float16*)(lds + GI_OFF) + srow * GI_STR;
    #pragma unroll
    for (int j = 0; j < 6; ++j) {
      const int c0 = skc * 8 + j * 128;
      const half8 a = *(const half8*)(ns + c0);
      const half8 bb = *(const half8*)(no_ + c0);
      half8 g;
      #pragma unroll
      for (int k = 0; k < 8; ++k) g[k] = gsh * a[k] + goh * bb[k];
      *(half8*)(giw + c0) = g;
    }
    __syncthreads();

    #pragma unroll
    for (int ksg = 0; ksg < 8; ++ksg) {
      half8 ah[4];
      #pragma unroll
      for (int rf = 0; rf < 4; ++rf)
        ah[rf] = *(const half8*)(&lds[((rf * 16 + lr) * 512 + ksg * 64 + lq * 16) ^ swm]);
      const int kk = 8 + ksg;
      const half8 br_ = *(const half8*)(wpe + (((0 * 16 + w) * 16 + kk) * 64 + l) * 8);
      const half8 bz_ = *(const half8*)(wpe + (((1 * 16 + w) * 16 + kk) * 64 + l) * 8);
      const half8 bn_ = *(const half8*)(wpe + (((2 * 16 + w) * 16 + kk) * 64 + l) * 8);
      #pragma unroll
      for (int rf = 0; rf < 4; ++rf)
        acc_r[rf] = __builtin_amdgcn_mfma_f32_16x16x32_f16(ah[rf], br_, acc_r[rf], 0, 0, 0);
      #pragma unroll
      for (int rf = 0; rf < 4; ++rf)
        acc_z[rf] = __builtin_amdgcn_mfma_f32_16x16x32_f16(ah[rf], bz_, acc_z[rf], 0, 0, 0);
      #pragma unroll
      for (int rf = 0; rf < 4; ++rf)
        acc_nh[rf] = __builtin_amdgcn_mfma_f32_16x16x32_f16(ah[rf], bn_, acc_nh[rf], 0, 0, 0);
    }

    const int col = w * 16 + lr;
    const float br = ebih[col] + ebhh[col];
    const float bz = ebih[256 + col] + ebhh[256 + col];
    const float bnx = ebih[512 + col];
    const float bnh = ebhh[512 + col];
    const _Float16* gir = (const _Float16*)(lds + GI_OFF);
    #pragma unroll
    for (int rf = 0; rf < 4; ++rf) {
      #pragma unroll
      for (int q = 0; q < 4; ++q) {
        const int rowl = rf * 16 + lq * 4 + q;
        const _Float16* gp = gir + rowl * GI_STR + col;
        const float r = sigf(acc_r[rf][q] + (float)gp[0] + br);
        const float z = sigf(acc_z[rf][q] + (float)gp[256] + bz);
        const float n = tanh_fast((float)gp[512] + bnx + r * (acc_nh[rf][q] + bnh));
        const float hv = eh[(rb + rowl) * D_DIM + col];
        eh[(rb + rowl) * D_DIM + col] = (1.0f - z) * n + z * hv;
      }
    }
  } else {
    // ================= MODE 1: node GRU (K-split h-first) =================
    const int rb = (blockIdx.x - EGRID) * BM;
    const int rowg = rb + srow;

    // stage h rows (f16), consumed fully
    {
      float4 pre[4];
      #pragma unroll
      for (int i = 0; i < 4; ++i)
        pre[i] = *(const float4*)(nh + rowg * D_DIM + (i >> 1) * 128 + skc * 8 + (i & 1) * 4);
      #pragma unroll
      for (int c = 0; c < 2; ++c) {
        half8 hh8;
        const float* f1 = (const float*)&pre[c * 2];
        #pragma unroll
        for (int j = 0; j < 8; ++j) hh8[j] = (_Float16)f1[j];
        *(half8*)(&lds[(srow * 1024 + 512 + c * 256 + skc * 16) ^ swz]) = hh8;
      }
    }
    __syncthreads();

    #pragma unroll
    for (int ksg = 0; ksg < 8; ++ksg) {
      half8 ah[4];
      #pragma unroll
      for (int rf = 0; rf < 4; ++rf)
        ah[rf] = *(const half8*)(&lds[((rf * 16 + lr) * 1024 + 512 + ksg * 64 + lq * 16) ^ swm]);
      const int kk = 8 + ksg;
      const half8 br_ = *(const half8*)(wpn + (((0 * 16 + w) * 16 + kk) * 64 + l) * 8);
      const half8 bz_ = *(const half8*)(wpn + (((1 * 16 + w) * 16 + kk) * 64 + l) * 8);
      const half8 bn_ = *(const half8*)(wpn + (((2 * 16 + w) * 16 + kk) * 64 + l) * 8);
      #pragma unroll
      for (int rf = 0; rf < 4; ++rf)
        acc_r[rf] = __builtin_amdgcn_mfma_f32_16x16x32_f16(ah[rf], br_, acc_r[rf], 0, 0, 0);
      #pragma unroll
      for (int rf = 0; rf < 4; ++rf)
        acc_z[rf] = __builtin_amdgcn_mfma_f32_16x16x32_f16(ah[rf], bz_, acc_z[rf], 0, 0, 0);
      #pragma unroll
      for (int rf = 0; rf < 4; ++rf)
        acc_nh[rf] = __builtin_amdgcn_mfma_f32_16x16x32_f16(ah[rf], bn_, acc_nh[rf], 0, 0, 0);
    }

    // stage x from node_msg (L2-hot), then x-half MFMAs
    #pragma unroll
    for (int c = 0; c < 2; ++c) {
      half8 hx;
      #pragma unroll
      for (int pq = 0; pq < 2; ++pq) {
        const float4 a = *(const float4*)(nmsg + rowg * D_DIM + c * 128 + skc * 8 + pq * 4);
        hx[pq * 4 + 0] = (_Float16)a.x; hx[pq * 4 + 1] = (_Float16)a.y;
        hx[pq * 4 + 2] = (_Float16)a.z; hx[pq * 4 + 3] = (_Float16)a.w;
      }
      *(half8*)(&lds[(srow * 1024 + 0 + c * 256 + skc * 16) ^ swz]) = hx;
    }
    __syncthreads();
    #pragma unroll
    for (int ksg = 0; ksg < 8; ++ksg) {
      half8 ah[4];
      #pragma unroll
      for (int rf = 0; rf < 4; ++rf)
        ah[rf] = *(const half8*)(&lds[((rf * 16 + lr) * 1024 + 0 + ksg * 64 + lq * 16) ^ swm]);
      const half8 br_ = *(const half8*)(wpn + (((0 * 16 + w) * 16 + ksg) * 64 + l) * 8);
      const half8 bz_ = *(const half8*)(wpn + (((1 * 16 + w) * 16 + ksg) * 64 + l) * 8);
      const half8 bn_ = *(const half8*)(wpn + (((2 * 16 + w) * 16 + ksg) * 64 + l) * 8);
      #pragma unroll
      for (int rf = 0; rf < 4; ++rf)
        acc_r[rf] = __builtin_amdgcn_mfma_f32_16x16x32_f16(ah[rf], br_, acc_r[rf], 0, 0, 0);
      #pragma unroll
      for (int rf = 0; rf < 4; ++rf)
        acc_z[rf] = __builtin_amdgcn_mfma_f32_16x16x32_f16(ah[rf], bz_, acc_z[rf], 0, 0, 0);
      #pragma unroll
      for (int rf = 0; rf < 4; ++rf)
        acc_nx[rf] = __builtin_amdgcn_mfma_f32_16x16x32_f16(ah[rf], bn_, acc_nx[rf], 0, 0, 0);
    }

    const int col = w * 16 + lr;
    const float br = nbih[col] + nbhh[col];
    const float bz = nbih[256 + col] + nbhh[256 + col];
    const float bnx = nbih[512 + col];
    const float bnh = nbhh[512 + col];
    #pragma unroll
    for (int rf = 0; rf < 4; ++rf) {
      #pragma unroll
      for (int q = 0; q < 4; ++q) {
        const int rowl = rf * 16 + lq * 4 + q;
        const float r = sigf(acc_r[rf][q] + br);
        const float z = sigf(acc_z[rf][q] + bz);
        const float n = tanh_fast(acc_nx[rf][q] + bnx + r * (acc_nh[rf][q] + bnh));
        const float hv = nh[(rb + rowl) * D_DIM + col];
        nh[(rb + rowl) * D_DIM + col] = (1.0f - z) * n + z * hv;
      }
    }
  }
}

// node_msg[b,n] = sum over 62 incident edges of gN*eh,
// gN = sig(dotA[b,sub] + eh . w_node_pool[256:512]) computed inline.
__global__ __launch_bounds__(256) void node_msg_kernel(
    const float* __restrict__ eh, const float* __restrict__ wnp,
    const float* __restrict__ dotA, float* __restrict__ nmsg) {
  __shared__ float sh[3][256];
  const int nr = blockIdx.x;  // 0..4095
  const int b = nr >> 5;
  const int n = nr & 31;
  const int wv = threadIdx.x >> 6;
  const int l = threadIdx.x & 63;
  const int base = b * NEDGE;
  const float4 w1b = ((const float4*)(wnp + 256))[l];

  float4 acc = {0.f, 0.f, 0.f, 0.f};
  for (int k = wv; k < 62; k += 4) {
    int e, sub;
    if (k < 31) {
      e = base + n * 31 + k;
      sub = n;
    } else {
      int i = k - 31;
      const int ip = (i < n) ? i : (i + 1);
      e = base + ip * 31 + ((n < ip) ? n : (n - 1));
      sub = ip;
    }
    const float4 ev = ((const float4*)(eh + e * D_DIM))[l];
    float p = dot4(ev, w1b);
    #pragma unroll
    for (int mm = 32; mm > 0; mm >>= 1) p += __shfl_xor(p, mm, 64);
    const float gN = sigf(dotA[b * NNODE + sub] + p);
    acc.x += gN * ev.x; acc.y += gN * ev.y; acc.z += gN * ev.z; acc.w += gN * ev.w;
  }
  if (wv > 0) *(float4*)(&sh[wv - 1][l * 4]) = acc;
  __syncthreads();
  if (wv == 0) {
    #pragma unroll
    for (int v = 0; v < 3; ++v) {
      const float4 o = *(const float4*)(&sh[v][l * 4]);
      acc.x += o.x; acc.y += o.y; acc.z += o.z; acc.w += o.w;
    }
    *(float4*)(nmsg + nr * D_DIM + l * 4) = acc;
  }
}

extern "C" void kernel_launch(void* const* d_in, const int* in_sizes, int n_in,
                              void* d_out, int out_size, void* d_ws, size_t ws_size,
                              hipStream_t stream) {
  const float* node_latents = (const float*)d_in[0];
  const float* edge_latents = (const float*)d_in[1];
  const float* node_Wih = (const float*)d_in[2];
  const float* node_Whh = (const float*)d_in[3];
  const float* node_bih = (const float*)d_in[4];
  const float* node_bhh = (const float*)d_in[5];
  const float* edge_Wih = (const float*)d_in[6];
  const float* edge_Whh = (const float*)d_in[7];
  const float* edge_bih = (const float*)d_in[8];
  const float* edge_bhh = (const float*)d_in[9];
  const float* w_node_pool = (const float*)d_in[10];
  const float* w_edge_sub = (const float*)d_in[11];
  const float* w_edge_obj = (const float*)d_in[12];

  float* nh = (float*)d_out;
  float* eh = (float*)d_out + NODE_ROWS * D_DIM;

  const int WPLANE = 48 * 16 * 64 * 8;  // 393216 f16 = 768KB
  _Float16* ph_n = (_Float16*)d_ws;
  _Float16* ph_e = ph_n + WPLANE;
  _Float16* NW = ph_e + WPLANE;                    // 4096 x 768 f16 = 6 MB
  float* fw = (float*)(NW + NODE_ROWS * 768);
  float* dotA = fw; fw += NODE_ROWS;
  float* dotS = fw; fw += NODE_ROWS;
  float* dotO = fw; fw += NODE_ROWS;
  float* node_msg = fw; fw += NODE_ROWS * D_DIM;   // total ~11.6 MB

  dim3 pg(48, 16);
  pack_w<<<pg, 64, 0, stream>>>(node_Wih, node_Whh, ph_n);
  pack_w<<<pg, 64, 0, stream>>>(edge_Wih, edge_Whh, ph_e);

  gru_init<<<EGRID + NGRID, 1024, 0, stream>>>(
      edge_latents, node_latents, eh, nh, ph_e, ph_n,
      edge_bih, edge_bhh, node_bih, node_bhh);

  for (int it = 0; it < 3; ++it) {
    gru_nw<<<NGRID, 1024, 0, stream>>>(
        nh, ph_e, NW, w_node_pool, w_edge_sub, w_edge_obj, dotA, dotS, dotO);
    node_msg_kernel<<<NODE_ROWS, 256, 0, stream>>>(eh, w_node_pool, dotA, node_msg);
    gru_iter<<<EGRID + NGRID, 1024, 0, stream>>>(
        eh, nh, node_msg, ph_e, ph_n,
        edge_bih, edge_bhh, node_bih, node_bhh,
        w_edge_sub + 256, w_edge_obj + 256, dotS, dotO, NW);
  }
}

// Round 17
// 658.144 us; speedup vs baseline: 1.2212x; 1.0873x over previous
//
#include <hip/hip_runtime.h>

// ---------------------------------------------------------------------------
// Round 16: f16 edge-hidden STATE (replace f32, not duplicate - R14's error).
//  - eh16 (65MB ws) is the edge-hidden representation between iterations.
//    gru_init writes it; gru_iter iters 0-1 read+write it; iter 2 (LAST)
//    writes f32 d_out. node_msg reads eh16 (halves its 260MB read).
//  - hv carry comes from the staged LDS f16 == the exact state (no global
//    re-read, no double rounding).
//  - All other structure = R15 (best, 716us): fused init, fused iter
//    (edge blocks + node blocks), gru_nw with fused dot3.
// ---------------------------------------------------------------------------

#define D_DIM 256
#define NNODE 32
#define NEDGE 992
#define EDGE_ROWS (128 * NEDGE)   // 126976
#define NODE_ROWS (128 * NNODE)   // 4096
#define BM 64
#define EGRID (EDGE_ROWS / BM)    // 1984
#define NGRID (NODE_ROWS / BM)    // 64
#define GI_OFF 32768
#define GI_STR 776

typedef _Float16 half8 __attribute__((ext_vector_type(8)));
typedef _Float16 half4v __attribute__((ext_vector_type(4)));
typedef __attribute__((ext_vector_type(4))) float f32x4;

__device__ __forceinline__ float sigf(float x) { return 1.0f / (1.0f + __expf(-x)); }
__device__ __forceinline__ float tanh_fast(float x) { return 2.0f / (1.0f + __expf(-2.0f * x)) - 1.0f; }
__device__ __forceinline__ float dot4(float4 a, float4 b) { return a.x*b.x + a.y*b.y + a.z*b.z + a.w*b.w; }

__global__ __launch_bounds__(64) void pack_w(const float* __restrict__ Wih,
                                             const float* __restrict__ Whh,
                                             _Float16* __restrict__ ph) {
  const int ct = blockIdx.x;
  const int ks = blockIdx.y;
  const int l = threadIdx.x;
  const int col = ct * 16 + (l & 15);
  const int kb = ks * 32 + (l >> 4) * 8;
  const float* src = (kb < 256) ? (Wih + col * 256 + kb) : (Whh + col * 256 + (kb - 256));
  half8 v;
  #pragma unroll
  for (int j = 0; j < 8; ++j) v[j] = (_Float16)src[j];
  *(half8*)(ph + ((ct * 16 + ks) * 64 + l) * 8) = v;
}

// ---- INIT GRU (h=0): edge blocks write eh16; node blocks write f32 nh ----
__global__ __launch_bounds__(1024, 4) void gru_init(
    const float* __restrict__ xe, const float* __restrict__ xn,
    _Float16* __restrict__ eh16, float* __restrict__ hn,
    const _Float16* __restrict__ wpe, const _Float16* __restrict__ wpn,
    const float* __restrict__ ebih, const float* __restrict__ ebhh,
    const float* __restrict__ nbih, const float* __restrict__ nbhh) {
  __shared__ __align__(16) unsigned char lds[32768];
  const bool edge = blockIdx.x < EGRID;
  const int bx = edge ? blockIdx.x : (blockIdx.x - EGRID);
  const float* xsrc = edge ? xe : xn;
  const _Float16* wp = edge ? wpe : wpn;
  const float* bih = edge ? ebih : nbih;
  const float* bhh = edge ? ebhh : nbhh;

  const int t = threadIdx.x;
  const int rb = bx * BM;
  const int srow = t >> 4;
  const int skc = t & 15;
  const int w = t >> 6;
  const int l = t & 63;
  const int lq = l >> 4;
  const int lr = l & 15;
  const int swm = (lr & 7) << 4;
  const int swz = (srow & 7) << 4;
  const int rowg = rb + srow;

  #pragma unroll
  for (int c = 0; c < 2; ++c) {
    half8 hx;
    #pragma unroll
    for (int pq = 0; pq < 2; ++pq) {
      const float4 a = *(const float4*)(xsrc + rowg * D_DIM + c * 128 + skc * 8 + pq * 4);
      hx[pq * 4 + 0] = (_Float16)a.x; hx[pq * 4 + 1] = (_Float16)a.y;
      hx[pq * 4 + 2] = (_Float16)a.z; hx[pq * 4 + 3] = (_Float16)a.w;
    }
    *(half8*)(&lds[(srow * 512 + c * 256 + skc * 16) ^ swz]) = hx;
  }
  __syncthreads();

  const f32x4 zz = {0.f, 0.f, 0.f, 0.f};
  f32x4 acc_r[4] = {zz, zz, zz, zz};
  f32x4 acc_z[4] = {zz, zz, zz, zz};
  f32x4 acc_nx[4] = {zz, zz, zz, zz};

  #pragma unroll
  for (int ksg = 0; ksg < 8; ++ksg) {
    half8 ah[4];
    #pragma unroll
    for (int rf = 0; rf < 4; ++rf)
      ah[rf] = *(const half8*)(&lds[((rf * 16 + lr) * 512 + ksg * 64 + lq * 16) ^ swm]);
    const half8 br_ = *(const half8*)(wp + (((0 * 16 + w) * 16 + ksg) * 64 + l) * 8);
    const half8 bz_ = *(const half8*)(wp + (((1 * 16 + w) * 16 + ksg) * 64 + l) * 8);
    const half8 bn_ = *(const half8*)(wp + (((2 * 16 + w) * 16 + ksg) * 64 + l) * 8);
    #pragma unroll
    for (int rf = 0; rf < 4; ++rf)
      acc_r[rf] = __builtin_amdgcn_mfma_f32_16x16x32_f16(ah[rf], br_, acc_r[rf], 0, 0, 0);
    #pragma unroll
    for (int rf = 0; rf < 4; ++rf)
      acc_z[rf] = __builtin_amdgcn_mfma_f32_16x16x32_f16(ah[rf], bz_, acc_z[rf], 0, 0, 0);
    #pragma unroll
    for (int rf = 0; rf < 4; ++rf)
      acc_nx[rf] = __builtin_amdgcn_mfma_f32_16x16x32_f16(ah[rf], bn_, acc_nx[rf], 0, 0, 0);
  }

  const int col = w * 16 + lr;
  const float br = bih[col] + bhh[col];
  const float bz = bih[256 + col] + bhh[256 + col];
  const float bnx = bih[512 + col];
  const float bnh = bhh[512 + col];

  if (edge) {
    _Float16 sv[16];
    #pragma unroll
    for (int rf = 0; rf < 4; ++rf) {
      #pragma unroll
      for (int q = 0; q < 4; ++q) {
        const float r = sigf(acc_r[rf][q] + br);
        const float z = sigf(acc_z[rf][q] + bz);
        const float n = tanh_fast(acc_nx[rf][q] + bnx + r * bnh);
        sv[rf * 4 + q] = (_Float16)((1.0f - z) * n);
      }
    }
    __syncthreads();
    #pragma unroll
    for (int rf = 0; rf < 4; ++rf) {
      #pragma unroll
      for (int q = 0; q < 4; ++q) {
        const int rowl = rf * 16 + lq * 4 + q;
        *(_Float16*)(&lds[(rowl * 512 + col * 2) ^ ((rowl & 7) << 4)]) = sv[rf * 4 + q];
      }
    }
    __syncthreads();
    #pragma unroll
    for (int p = 0; p < 2; ++p) {
      const int c = t + p * 1024;
      const int row = c >> 5;
      const int kc = c & 31;
      *(uint4*)(eh16 + (rb + row) * 256 + kc * 8) =
          *(const uint4*)(&lds[(row * 512 + kc * 16) ^ ((row & 7) << 4)]);
    }
  } else {
    #pragma unroll
    for (int rf = 0; rf < 4; ++rf) {
      #pragma unroll
      for (int q = 0; q < 4; ++q) {
        const int rowl = rf * 16 + lq * 4 + q;
        const float r = sigf(acc_r[rf][q] + br);
        const float z = sigf(acc_z[rf][q] + bz);
        const float n = tanh_fast(acc_nx[rf][q] + bnx + r * bnh);
        hn[(rb + rowl) * D_DIM + col] = (1.0f - z) * n;
      }
    }
  }
}

// ---- NW = nh @ edge_WihT (f16 out) with dot3 fused into staging ----
__global__ __launch_bounds__(1024, 4) void gru_nw(
    const float* __restrict__ nh, const _Float16* __restrict__ wp,
    _Float16* __restrict__ nw,
    const float* __restrict__ wnp, const float* __restrict__ wes,
    const float* __restrict__ weo,
    float* __restrict__ dA, float* __restrict__ dS, float* __restrict__ dO) {
  __shared__ __align__(16) unsigned char lds[32768];
  const int t = threadIdx.x;
  const int rb = blockIdx.x * BM;
  const int srow = t >> 4;
  const int skc = t & 15;
  const int w = t >> 6;
  const int l = t & 63;
  const int lq = l >> 4;
  const int lr = l & 15;
  const int swm = (lr & 7) << 4;
  const int swz = (srow & 7) << 4;
  const int rowg = rb + srow;

  float4 xa[4];
  #pragma unroll
  for (int i = 0; i < 4; ++i)
    xa[i] = *(const float4*)(nh + rowg * D_DIM + (i >> 1) * 128 + skc * 8 + (i & 1) * 4);
  #pragma unroll
  for (int c = 0; c < 2; ++c) {
    half8 hx;
    const float* f0 = (const float*)&xa[c * 2];
    #pragma unroll
    for (int j = 0; j < 8; ++j) hx[j] = (_Float16)f0[j];
    *(half8*)(&lds[(srow * 512 + c * 256 + skc * 16) ^ swz]) = hx;
  }
  float p1 = 0.f, p2 = 0.f, p3 = 0.f;
  #pragma unroll
  for (int i = 0; i < 4; ++i) {
    const int k0 = (i >> 1) * 128 + skc * 8 + (i & 1) * 4;
    p1 += dot4(xa[i], *(const float4*)(wnp + k0));
    p2 += dot4(xa[i], *(const float4*)(wes + k0));
    p3 += dot4(xa[i], *(const float4*)(weo + k0));
  }
  #pragma unroll
  for (int mm = 1; mm < 16; mm <<= 1) {
    p1 += __shfl_xor(p1, mm, 16);
    p2 += __shfl_xor(p2, mm, 16);
    p3 += __shfl_xor(p3, mm, 16);
  }
  if (skc == 0) { dA[rowg] = p1; dS[rowg] = p2; dO[rowg] = p3; }
  __syncthreads();

  const f32x4 zz = {0.f, 0.f, 0.f, 0.f};
  f32x4 acc_r[4] = {zz, zz, zz, zz};
  f32x4 acc_z[4] = {zz, zz, zz, zz};
  f32x4 acc_nx[4] = {zz, zz, zz, zz};

  #pragma unroll
  for (int ksg = 0; ksg < 8; ++ksg) {
    half8 ah[4];
    #pragma unroll
    for (int rf = 0; rf < 4; ++rf)
      ah[rf] = *(const half8*)(&lds[((rf * 16 + lr) * 512 + ksg * 64 + lq * 16) ^ swm]);
    const half8 br_ = *(const half8*)(wp + (((0 * 16 + w) * 16 + ksg) * 64 + l) * 8);
    const half8 bz_ = *(const half8*)(wp + (((1 * 16 + w) * 16 + ksg) * 64 + l) * 8);
    const half8 bn_ = *(const half8*)(wp + (((2 * 16 + w) * 16 + ksg) * 64 + l) * 8);
    #pragma unroll
    for (int rf = 0; rf < 4; ++rf)
      acc_r[rf] = __builtin_amdgcn_mfma_f32_16x16x32_f16(ah[rf], br_, acc_r[rf], 0, 0, 0);
    #pragma unroll
    for (int rf = 0; rf < 4; ++rf)
      acc_z[rf] = __builtin_amdgcn_mfma_f32_16x16x32_f16(ah[rf], bz_, acc_z[rf], 0, 0, 0);
    #pragma unroll
    for (int rf = 0; rf < 4; ++rf)
      acc_nx[rf] = __builtin_amdgcn_mfma_f32_16x16x32_f16(ah[rf], bn_, acc_nx[rf], 0, 0, 0);
  }

  const int col = w * 16 + lr;
  #pragma unroll
  for (int rf = 0; rf < 4; ++rf) {
    #pragma unroll
    for (int q = 0; q < 4; ++q) {
      const int rowl = rf * 16 + lq * 4 + q;
      _Float16* np = nw + (rb + rowl) * 768 + col;
      np[0]   = (_Float16)acc_r[rf][q];
      np[256] = (_Float16)acc_z[rf][q];
      np[512] = (_Float16)acc_nx[rf][q];
    }
  }
}

// ---- fused iteration GRU: edge blocks [0,EGRID) on eh16, node blocks rest ----
template <bool LAST>
__global__ __launch_bounds__(1024, 4) void gru_iter(
    _Float16* __restrict__ eh16, float* __restrict__ ehf,
    float* __restrict__ nh, const float* __restrict__ nmsg,
    const _Float16* __restrict__ wpe, const _Float16* __restrict__ wpn,
    const float* __restrict__ ebih, const float* __restrict__ ebhh,
    const float* __restrict__ nbih, const float* __restrict__ nbhh,
    const float* __restrict__ wesb, const float* __restrict__ weob,
    const float* __restrict__ dotS, const float* __restrict__ dotO,
    const _Float16* __restrict__ nw) {
  __shared__ __align__(16) unsigned char lds[32768 + BM * GI_STR * 2];

  const int t = threadIdx.x;
  const int srow = t >> 4;
  const int skc = t & 15;
  const int w = t >> 6;
  const int l = t & 63;
  const int lq = l >> 4;
  const int lr = l & 15;
  const int swm = (lr & 7) << 4;
  const int swz = (srow & 7) << 4;

  const f32x4 zz = {0.f, 0.f, 0.f, 0.f};
  f32x4 acc_r[4] = {zz, zz, zz, zz};
  f32x4 acc_z[4] = {zz, zz, zz, zz};
  f32x4 acc_nx[4] = {zz, zz, zz, zz};
  f32x4 acc_nh[4] = {zz, zz, zz, zz};

  if (blockIdx.x < EGRID) {
    // ================= edge GRU (f16 state) =================
    const int rb = blockIdx.x * BM;
    const int rowg = rb + srow;
    const int b = rowg / NEDGE;
    const int e = rowg - b * NEDGE;
    const int si = e / 31;
    const int m = e - si * 31;
    const int ob = (m < si) ? m : (m + 1);

    // stage eh16 (verbatim f16 copy) + gate dots from cvt'd values
    const uint4 v0 = *(const uint4*)(eh16 + rowg * 256 + skc * 8);
    const uint4 v1 = *(const uint4*)(eh16 + rowg * 256 + 128 + skc * 8);
    *(uint4*)(&lds[(srow * 512 + skc * 16) ^ swz]) = v0;
    *(uint4*)(&lds[(srow * 512 + 256 + skc * 16) ^ swz]) = v1;
    float pS = 0.f, pO = 0.f;
    {
      const _Float16* f0 = (const _Float16*)&v0;
      const _Float16* f1 = (const _Float16*)&v1;
      #pragma unroll
      for (int j = 0; j < 8; ++j) {
        const float a = (float)f0[j];
        const float bb = (float)f1[j];
        pS += a * wesb[skc * 8 + j] + bb * wesb[128 + skc * 8 + j];
        pO += a * weob[skc * 8 + j] + bb * weob[128 + skc * 8 + j];
      }
    }
    #pragma unroll
    for (int mm = 1; mm < 16; mm <<= 1) {
      pS += __shfl_xor(pS, mm, 16);
      pO += __shfl_xor(pO, mm, 16);
    }
    const float gs = sigf(dotS[b * NNODE + si] + pS);
    const float go = sigf(dotO[b * NNODE + ob] + pO);
    const _Float16 gsh = (_Float16)gs, goh = (_Float16)go;
    const _Float16* ns = nw + (b * NNODE + si) * 768;
    const _Float16* no_ = nw + (b * NNODE + ob) * 768;
    _Float16* giw = (_Float16*)(lds + GI_OFF) + srow * GI_STR;
    #pragma unroll
    for (int j = 0; j < 6; ++j) {
      const int c0 = skc * 8 + j * 128;
      const half8 a = *(const half8*)(ns + c0);
      const half8 bb = *(const half8*)(no_ + c0);
      half8 g;
      #pragma unroll
      for (int k = 0; k < 8; ++k) g[k] = gsh * a[k] + goh * bb[k];
      *(half8*)(giw + c0) = g;
    }
    __syncthreads();

    #pragma unroll
    for (int ksg = 0; ksg < 8; ++ksg) {
      half8 ah[4];
      #pragma unroll
      for (int rf = 0; rf < 4; ++rf)
        ah[rf] = *(const half8*)(&lds[((rf * 16 + lr) * 512 + ksg * 64 + lq * 16) ^ swm]);
      const int kk = 8 + ksg;
      const half8 br_ = *(const half8*)(wpe + (((0 * 16 + w) * 16 + kk) * 64 + l) * 8);
      const half8 bz_ = *(const half8*)(wpe + (((1 * 16 + w) * 16 + kk) * 64 + l) * 8);
      const half8 bn_ = *(const half8*)(wpe + (((2 * 16 + w) * 16 + kk) * 64 + l) * 8);
      #pragma unroll
      for (int rf = 0; rf < 4; ++rf)
        acc_r[rf] = __builtin_amdgcn_mfma_f32_16x16x32_f16(ah[rf], br_, acc_r[rf], 0, 0, 0);
      #pragma unroll
      for (int rf = 0; rf < 4; ++rf)
        acc_z[rf] = __builtin_amdgcn_mfma_f32_16x16x32_f16(ah[rf], bz_, acc_z[rf], 0, 0, 0);
      #pragma unroll
      for (int rf = 0; rf < 4; ++rf)
        acc_nh[rf] = __builtin_amdgcn_mfma_f32_16x16x32_f16(ah[rf], bn_, acc_nh[rf], 0, 0, 0);
    }

    const int col = w * 16 + lr;
    const float br = ebih[col] + ebhh[col];
    const float bz = ebih[256 + col] + ebhh[256 + col];
    const float bnx = ebih[512 + col];
    const float bnh = ebhh[512 + col];
    const _Float16* gir = (const _Float16*)(lds + GI_OFF);
    _Float16 sv[16];
    #pragma unroll
    for (int rf = 0; rf < 4; ++rf) {
      #pragma unroll
      for (int q = 0; q < 4; ++q) {
        const int rowl = rf * 16 + lq * 4 + q;
        const _Float16* gp = gir + rowl * GI_STR + col;
        const float r = sigf(acc_r[rf][q] + (float)gp[0] + br);
        const float z = sigf(acc_z[rf][q] + (float)gp[256] + bz);
        const float n = tanh_fast((float)gp[512] + bnx + r * (acc_nh[rf][q] + bnh));
        const float hv =
            (float)*(const _Float16*)(&lds[(rowl * 512 + col * 2) ^ ((rowl & 7) << 4)]);
        const float out = (1.0f - z) * n + z * hv;
        if constexpr (LAST) {
          ehf[(rb + rowl) * D_DIM + col] = out;
        } else {
          sv[rf * 4 + q] = (_Float16)out;
        }
      }
    }
    if constexpr (!LAST) {
      __syncthreads();
      #pragma unroll
      for (int rf = 0; rf < 4; ++rf) {
        #pragma unroll
        for (int q = 0; q < 4; ++q) {
          const int rowl = rf * 16 + lq * 4 + q;
          *(_Float16*)(&lds[(rowl * 512 + col * 2) ^ ((rowl & 7) << 4)]) = sv[rf * 4 + q];
        }
      }
      __syncthreads();
      #pragma unroll
      for (int p = 0; p < 2; ++p) {
        const int c = t + p * 1024;
        const int row = c >> 5;
        const int kc = c & 31;
        *(uint4*)(eh16 + (rb + row) * 256 + kc * 8) =
            *(const uint4*)(&lds[(row * 512 + kc * 16) ^ ((row & 7) << 4)]);
      }
    }
  } else {
    // ================= node GRU (f32 state, K-split h-first) =================
    const int rb = (blockIdx.x - EGRID) * BM;
    const int rowg = rb + srow;

    {
      float4 pre[4];
      #pragma unroll
      for (int i = 0; i < 4; ++i)
        pre[i] = *(const float4*)(nh + rowg * D_DIM + (i >> 1) * 128 + skc * 8 + (i & 1) * 4);
      #pragma unroll
      for (int c = 0; c < 2; ++c) {
        half8 hh8;
        const float* f1 = (const float*)&pre[c * 2];
        #pragma unroll
        for (int j = 0; j < 8; ++j) hh8[j] = (_Float16)f1[j];
        *(half8*)(&lds[(srow * 1024 + 512 + c * 256 + skc * 16) ^ swz]) = hh8;
      }
    }
    __syncthreads();

    #pragma unroll
    for (int ksg = 0; ksg < 8; ++ksg) {
      half8 ah[4];
      #pragma unroll
      for (int rf = 0; rf < 4; ++rf)
        ah[rf] = *(const half8*)(&lds[((rf * 16 + lr) * 1024 + 512 + ksg * 64 + lq * 16) ^ swm]);
      const int kk = 8 + ksg;
      const half8 br_ = *(const half8*)(wpn + (((0 * 16 + w) * 16 + kk) * 64 + l) * 8);
      const half8 bz_ = *(const half8*)(wpn + (((1 * 16 + w) * 16 + kk) * 64 + l) * 8);
      const half8 bn_ = *(const half8*)(wpn + (((2 * 16 + w) * 16 + kk) * 64 + l) * 8);
      #pragma unroll
      for (int rf = 0; rf < 4; ++rf)
        acc_r[rf] = __builtin_amdgcn_mfma_f32_16x16x32_f16(ah[rf], br_, acc_r[rf], 0, 0, 0);
      #pragma unroll
      for (int rf = 0; rf < 4; ++rf)
        acc_z[rf] = __builtin_amdgcn_mfma_f32_16x16x32_f16(ah[rf], bz_, acc_z[rf], 0, 0, 0);
      #pragma unroll
      for (int rf = 0; rf < 4; ++rf)
        acc_nh[rf] = __builtin_amdgcn_mfma_f32_16x16x32_f16(ah[rf], bn_, acc_nh[rf], 0, 0, 0);
    }

    #pragma unroll
    for (int c = 0; c < 2; ++c) {
      half8 hx;
      #pragma unroll
      for (int pq = 0; pq < 2; ++pq) {
        const float4 a = *(const float4*)(nmsg + rowg * D_DIM + c * 128 + skc * 8 + pq * 4);
        hx[pq * 4 + 0] = (_Float16)a.x; hx[pq * 4 + 1] = (_Float16)a.y;
        hx[pq * 4 + 2] = (_Float16)a.z; hx[pq * 4 + 3] = (_Float16)a.w;
      }
      *(half8*)(&lds[(srow * 1024 + 0 + c * 256 + skc * 16) ^ swz]) = hx;
    }
    __syncthreads();
    #pragma unroll
    for (int ksg = 0; ksg < 8; ++ksg) {
      half8 ah[4];
      #pragma unroll
      for (int rf = 0; rf < 4; ++rf)
        ah[rf] = *(const half8*)(&lds[((rf * 16 + lr) * 1024 + 0 + ksg * 64 + lq * 16) ^ swm]);
      const half8 br_ = *(const half8*)(wpn + (((0 * 16 + w) * 16 + ksg) * 64 + l) * 8);
      const half8 bz_ = *(const half8*)(wpn + (((1 * 16 + w) * 16 + ksg) * 64 + l) * 8);
      const half8 bn_ = *(const half8*)(wpn + (((2 * 16 + w) * 16 + ksg) * 64 + l) * 8);
      #pragma unroll
      for (int rf = 0; rf < 4; ++rf)
        acc_r[rf] = __builtin_amdgcn_mfma_f32_16x16x32_f16(ah[rf], br_, acc_r[rf], 0, 0, 0);
      #pragma unroll
      for (int rf = 0; rf < 4; ++rf)
        acc_z[rf] = __builtin_amdgcn_mfma_f32_16x16x32_f16(ah[rf], bz_, acc_z[rf], 0, 0, 0);
      #pragma unroll
      for (int rf = 0; rf < 4; ++rf)
        acc_nx[rf] = __builtin_amdgcn_mfma_f32_16x16x32_f16(ah[rf], bn_, acc_nx[rf], 0, 0, 0);
    }

    const int col = w * 16 + lr;
    const float br = nbih[col] + nbhh[col];
    const float bz = nbih[256 + col] + nbhh[256 + col];
    const float bnx = nbih[512 + col];
    const float bnh = nbhh[512 + col];
    #pragma unroll
    for (int rf = 0; rf < 4; ++rf) {
      #pragma unroll
      for (int q = 0; q < 4; ++q) {
        const int rowl = rf * 16 + lq * 4 + q;
        const float r = sigf(acc_r[rf][q] + br);
        const float z = sigf(acc_z[rf][q] + bz);
        const float n = tanh_fast(acc_nx[rf][q] + bnx + r * (acc_nh[rf][q] + bnh));
        const float hv = nh[(rb + rowl) * D_DIM + col];
        nh[(rb + rowl) * D_DIM + col] = (1.0f - z) * n + z * hv;
      }
    }
  }
}

// node_msg from eh16: gN inline; halved read traffic.
__global__ __launch_bounds__(256) void node_msg_kernel(
    const _Float16* __restrict__ eh16, const float* __restrict__ wnp,
    const float* __restrict__ dotA, float* __restrict__ nmsg) {
  __shared__ float sh[3][256];
  const int nr = blockIdx.x;
  const int b = nr >> 5;
  const int n = nr & 31;
  const int wv = threadIdx.x >> 6;
  const int l = threadIdx.x & 63;
  const int base = b * NEDGE;
  const float4 w1b = ((const float4*)(wnp + 256))[l];

  float4 acc = {0.f, 0.f, 0.f, 0.f};
  for (int k = wv; k < 62; k += 4) {
    int e, sub;
    if (k < 31) {
      e = base + n * 31 + k;
      sub = n;
    } else {
      int i = k - 31;
      const int ip = (i < n) ? i : (i + 1);
      e = base + ip * 31 + ((n < ip) ? n : (n - 1));
      sub = ip;
    }
    const half4v hv4 = ((const half4v*)(eh16 + e * 256))[l];
    float4 ev;
    ev.x = (float)hv4[0]; ev.y = (float)hv4[1];
    ev.z = (float)hv4[2]; ev.w = (float)hv4[3];
    float p = dot4(ev, w1b);
    #pragma unroll
    for (int mm = 32; mm > 0; mm >>= 1) p += __shfl_xor(p, mm, 64);
    const float gN = sigf(dotA[b * NNODE + sub] + p);
    acc.x += gN * ev.x; acc.y += gN * ev.y; acc.z += gN * ev.z; acc.w += gN * ev.w;
  }
  if (wv > 0) *(float4*)(&sh[wv - 1][l * 4]) = acc;
  __syncthreads();
  if (wv == 0) {
    #pragma unroll
    for (int v = 0; v < 3; ++v) {
      const float4 o = *(const float4*)(&sh[v][l * 4]);
      acc.x += o.x; acc.y += o.y; acc.z += o.z; acc.w += o.w;
    }
    *(float4*)(nmsg + nr * D_DIM + l * 4) = acc;
  }
}

extern "C" void kernel_launch(void* const* d_in, const int* in_sizes, int n_in,
                              void* d_out, int out_size, void* d_ws, size_t ws_size,
                              hipStream_t stream) {
  const float* node_latents = (const float*)d_in[0];
  const float* edge_latents = (const float*)d_in[1];
  const float* node_Wih = (const float*)d_in[2];
  const float* node_Whh = (const float*)d_in[3];
  const float* node_bih = (const float*)d_in[4];
  const float* node_bhh = (const float*)d_in[5];
  const float* edge_Wih = (const float*)d_in[6];
  const float* edge_Whh = (const float*)d_in[7];
  const float* edge_bih = (const float*)d_in[8];
  const float* edge_bhh = (const float*)d_in[9];
  const float* w_node_pool = (const float*)d_in[10];
  const float* w_edge_sub = (const float*)d_in[11];
  const float* w_edge_obj = (const float*)d_in[12];

  float* nh = (float*)d_out;
  float* eh = (float*)d_out + NODE_ROWS * D_DIM;

  const int WPLANE = 48 * 16 * 64 * 8;  // 768KB
  _Float16* ph_n = (_Float16*)d_ws;
  _Float16* ph_e = ph_n + WPLANE;
  _Float16* NW = ph_e + WPLANE;                    // 6 MB
  _Float16* eh16 = NW + NODE_ROWS * 768;           // 65 MB
  float* fw = (float*)(eh16 + (size_t)EDGE_ROWS * D_DIM);
  float* dotA = fw; fw += NODE_ROWS;
  float* dotS = fw; fw += NODE_ROWS;
  float* dotO = fw; fw += NODE_ROWS;
  float* node_msg = fw; fw += NODE_ROWS * D_DIM;   // total ~77 MB

  dim3 pg(48, 16);
  pack_w<<<pg, 64, 0, stream>>>(node_Wih, node_Whh, ph_n);
  pack_w<<<pg, 64, 0, stream>>>(edge_Wih, edge_Whh, ph_e);

  gru_init<<<EGRID + NGRID, 1024, 0, stream>>>(
      edge_latents, node_latents, eh16, nh, ph_e, ph_n,
      edge_bih, edge_bhh, node_bih, node_bhh);

  for (int it = 0; it < 3; ++it) {
    gru_nw<<<NGRID, 1024, 0, stream>>>(
        nh, ph_e, NW, w_node_pool, w_edge_sub, w_edge_obj, dotA, dotS, dotO);
    node_msg_kernel<<<NODE_ROWS, 256, 0, stream>>>(eh16, w_node_pool, dotA, node_msg);
    if (it < 2)
      gru_iter<false><<<EGRID + NGRID, 1024, 0, stream>>>(
          eh16, eh, nh, node_msg, ph_e, ph_n,
          edge_bih, edge_bhh, node_bih, node_bhh,
          w_edge_sub + 256, w_edge_obj + 256, dotS, dotO, NW);
    else
      gru_iter<true><<<EGRID + NGRID, 1024, 0, stream>>>(
          eh16, eh, nh, node_msg, ph_e, ph_n,
          edge_bih, edge_bhh, node_bih, node_bhh,
          w_edge_sub + 256, w_edge_obj + 256, dotS, dotO, NW);
  }
}